// Round 1
// baseline (5078.071 us; speedup 1.0000x reference)
//
#include <hip/hip_runtime.h>
#include <hip/hip_bf16.h>

#define NNODES 100000
#define FD 128
#define NEDGES 640000
#define BN_BLOCKS 512

typedef __bf16 bf16x8 __attribute__((ext_vector_type(8)));
typedef float f32x4 __attribute__((ext_vector_type(4)));

__device__ __forceinline__ bf16x8 cvt8(float4 a, float4 b) {
  bf16x8 r;
  r[0] = (__bf16)a.x; r[1] = (__bf16)a.y; r[2] = (__bf16)a.z; r[3] = (__bf16)a.w;
  r[4] = (__bf16)b.x; r[5] = (__bf16)b.y; r[6] = (__bf16)b.z; r[7] = (__bf16)b.w;
  return r;
}

// out[M x 128] = A0 @ W0^T (+ A1 @ W1^T) + bias + addsrc, optional relu.
// A layout M x 128 f32. W layout 128(N) x 128(K) f32 (multiply by W^T).
// Each block: 2 chunks of 128 rows; each wave: 32 rows (2 MFMA row-tiles) x 128 cols.
// Weights live in registers as bf16 fragments (128 VGPR/lane).
template <bool RELU, bool ADD, bool OUTBF16, bool TWOA>
__global__ __launch_bounds__(256, 2) void gemm_k(
    const float* __restrict__ A0, const float* __restrict__ A1,
    const float* __restrict__ W0, const float* __restrict__ W1,
    const float* __restrict__ bias, const float* __restrict__ addsrc,
    void* __restrict__ outp, int M) {
  const int wid = threadIdx.x >> 6;
  const int lane = threadIdx.x & 63;
  const int lr = lane & 15;   // A-row / B-col / D-col within 16-tile
  const int lg = lane >> 4;   // k-group (8 consecutive k) / D row-quad

  for (int chunk = 0; chunk < 2; ++chunk) {
    const int rbase = blockIdx.x * 256 + chunk * 128 + wid * 32;
    if (rbase >= M) break;  // per-wave uniform, no barriers in kernel

    f32x4 acc[2][8];
#pragma unroll
    for (int t = 0; t < 2; ++t)
#pragma unroll
      for (int c = 0; c < 8; ++c) acc[t][c] = (f32x4){0.f, 0.f, 0.f, 0.f};

#pragma unroll
    for (int pass = 0; pass < (TWOA ? 2 : 1); ++pass) {
      const float* __restrict__ A = (TWOA && pass) ? A1 : A0;
      const float* __restrict__ W = (TWOA && pass) ? W1 : W0;

      // Stage full weight matrix into registers as B-fragments:
      // B[k][n] = W[n][k]; lane holds n = c*16+lr, k = kk*32 + lg*8 .. +7
      bf16x8 bf[8][4];
#pragma unroll
      for (int c = 0; c < 8; ++c)
#pragma unroll
        for (int kk = 0; kk < 4; ++kk) {
          const float* p = W + (c * 16 + lr) * FD + kk * 32 + lg * 8;
          float4 x = *(const float4*)p;
          float4 y = *(const float4*)(p + 4);
          bf[c][kk] = cvt8(x, y);
        }

#pragma unroll
      for (int t = 0; t < 2; ++t) {
        int row = rbase + t * 16 + lr;
        if (row > M - 1) row = M - 1;  // clamp; stores are guarded below
        const float* ap = A + (long)row * FD + lg * 8;
#pragma unroll
        for (int kk = 0; kk < 4; ++kk) {
          float4 x = *(const float4*)(ap + kk * 32);
          float4 y = *(const float4*)(ap + kk * 32 + 4);
          bf16x8 af = cvt8(x, y);
#pragma unroll
          for (int c = 0; c < 8; ++c)
            acc[t][c] = __builtin_amdgcn_mfma_f32_16x16x32_bf16(af, bf[c][kk], acc[t][c], 0, 0, 0);
        }
      }
    }

    // Epilogue: D element (row = rbase + t*16 + lg*4 + j, col = c*16 + lr)
#pragma unroll
    for (int t = 0; t < 2; ++t)
#pragma unroll
      for (int j = 0; j < 4; ++j) {
        const int row = rbase + t * 16 + lg * 4 + j;
        if (row < M) {
#pragma unroll
          for (int c = 0; c < 8; ++c) {
            const int col = c * 16 + lr;
            float v = acc[t][c][j];
            if (bias) v += bias[col];
            if (ADD) v += addsrc[(long)row * FD + col];
            if (RELU) v = v > 0.f ? v : 0.f;
            if (OUTBF16)
              ((__bf16*)outp)[(long)row * FD + col] = (__bf16)v;
            else
              ((float*)outp)[(long)row * FD + col] = v;
          }
        }
      }
  }
}

// segment-max scatter: agg[dst] = max(agg[dst], m[src]) per feature.
// m >= 0 (post-relu) and agg zero-initialized, so int atomicMax on float bits
// is exact, and "no in-edge -> 0" falls out of the init.
__global__ __launch_bounds__(256) void scatter_max_k(
    const __bf16* __restrict__ m, const int* __restrict__ src,
    const int* __restrict__ dst, unsigned int* __restrict__ agg, int nE) {
  const long idx = (long)blockIdx.x * 256 + threadIdx.x;
  const int e = (int)(idx >> 5);
  if (e >= nE) return;
  const int fg = ((int)idx & 31) * 4;
  const int s = src[e];
  const int d = dst[e];
  const unsigned short* mp = (const unsigned short*)m + (long)s * FD + fg;
  ushort4 u = *(const ushort4*)mp;
  unsigned int* base = agg + (long)d * FD + fg;
  unsigned short uv[4] = {u.x, u.y, u.z, u.w};
#pragma unroll
  for (int j = 0; j < 4; ++j) {
    const unsigned int vb = ((unsigned int)uv[j]) << 16;
    if (vb > base[j]) atomicMax((int*)&base[j], (int)vb);  // pre-check cuts atomics
  }
}

__global__ __launch_bounds__(128) void bn_partial_k(const float* __restrict__ h,
                                                    float* __restrict__ ps,
                                                    float* __restrict__ pss) {
  const int f = threadIdx.x;
  float s = 0.f, ss = 0.f;
  for (int r = blockIdx.x; r < NNODES; r += BN_BLOCKS) {
    float x = h[(long)r * FD + f];
    s += x;
    ss += x * x;
  }
  ps[blockIdx.x * FD + f] = s;
  pss[blockIdx.x * FD + f] = ss;
}

__global__ __launch_bounds__(128) void bn_final_k(const float* __restrict__ ps,
                                                  const float* __restrict__ pss,
                                                  const float* __restrict__ gamma,
                                                  const float* __restrict__ beta,
                                                  float* __restrict__ scsh) {
  const int f = threadIdx.x;
  float s = 0.f, ss = 0.f;
  for (int b = 0; b < BN_BLOCKS; ++b) {
    s += ps[b * FD + f];
    ss += pss[b * FD + f];
  }
  const float mu = s / (float)NNODES;
  const float var = ss / (float)NNODES - mu * mu;
  const float sc = rsqrtf(var + 1e-5f) * gamma[f];
  scsh[f] = sc;
  scsh[FD + f] = beta[f] - mu * sc;
}

__global__ __launch_bounds__(256) void bn_apply_relu_k(float* __restrict__ h,
                                                       const float* __restrict__ scsh) {
  const long base = ((long)blockIdx.x * 256 + threadIdx.x) * 4;
  if (base >= (long)NNODES * FD) return;
  const int f = (int)(base & (FD - 1));
  float4 x = *(float4*)(h + base);
  const float4 sc = *(const float4*)(scsh + f);
  const float4 sh = *(const float4*)(scsh + FD + f);
  float4 y;
  y.x = fmaxf(x.x * sc.x + sh.x, 0.f);
  y.y = fmaxf(x.y * sc.y + sh.y, 0.f);
  y.z = fmaxf(x.z * sc.z + sh.z, 0.f);
  y.w = fmaxf(x.w * sc.w + sh.w, 0.f);
  *(float4*)(h + base) = y;
}

__global__ __launch_bounds__(256) void zero_k(float4* __restrict__ p, long n4) {
  const long i = (long)blockIdx.x * 256 + threadIdx.x;
  if (i < n4) p[i] = (float4){0.f, 0.f, 0.f, 0.f};
}

extern "C" void kernel_launch(void* const* d_in, const int* in_sizes, int n_in,
                              void* d_out, int out_size, void* d_ws, size_t ws_size,
                              hipStream_t stream) {
  const float* feat = (const float*)d_in[0];
  const int* edges = (const int*)d_in[1];
  const float* Wp1 = (const float*)d_in[2];
  const float* bp1 = (const float*)d_in[3];
  const float* Ws1 = (const float*)d_in[4];
  const float* Wn1 = (const float*)d_in[5];
  const float* b1 = (const float*)d_in[6];
  const float* gamma = (const float*)d_in[7];
  const float* beta = (const float*)d_in[8];
  const float* Wp2 = (const float*)d_in[9];
  const float* bp2 = (const float*)d_in[10];
  const float* Ws2 = (const float*)d_in[11];
  const float* Wn2 = (const float*)d_in[12];
  const float* b2 = (const float*)d_in[13];

  // workspace layout (all 256B-aligned offsets); total ~154.2 MB
  char* w = (char*)d_ws;
  __bf16* m1 = (__bf16*)w;                       // 25.6 MB  bf16 [N][128]
  float* hs1 = (float*)(w + 25600000);           // 51.2 MB  f32  [N][128]
  float* agg = (float*)(w + 76800000);           // 51.2 MB  f32  [N][128]
  __bf16* m2 = (__bf16*)(w + 128000000);         // 25.6 MB  bf16 [N][128]
  float* ps = (float*)(w + 153600000);           // 256 KB
  float* pss = ps + BN_BLOCKS * FD;              // 256 KB
  float* scsh = pss + BN_BLOCKS * FD;            // 1 KB

  const dim3 blk(256);
  const int gemmGrid = (NNODES + 255) / 256;
  const int zeroGrid = (int)(((long)NNODES * FD / 4 + 255) / 256);
  const long sthreads = (long)NEDGES * 32;
  const int scatGrid = (int)((sthreads + 255) / 256);

  // graph-independent: m1 = relu(feat@Wp1^T + bp1), hs1 = feat@Ws1^T + b1
  gemm_k<true, false, true, false><<<gemmGrid, blk, 0, stream>>>(
      feat, nullptr, Wp1, nullptr, bp1, nullptr, m1, NNODES);
  gemm_k<false, false, false, false><<<gemmGrid, blk, 0, stream>>>(
      feat, nullptr, Ws1, nullptr, b1, nullptr, hs1, NNODES);

  for (int g = 0; g < 3; ++g) {
    const int* src = edges + (long)g * 2 * NEDGES;
    const int* dst = src + NEDGES;
    float* outg = (float*)d_out + (long)g * NNODES * FD;

    zero_k<<<zeroGrid, blk, 0, stream>>>((float4*)agg, (long)NNODES * FD / 4);
    scatter_max_k<<<scatGrid, blk, 0, stream>>>(m1, src, dst, (unsigned int*)agg, NEDGES);

    // h = hs1 + agg@Wn1^T  -> outg (f32)
    gemm_k<false, true, false, false><<<gemmGrid, blk, 0, stream>>>(
        agg, nullptr, Wn1, nullptr, nullptr, hs1, outg, NNODES);

    bn_partial_k<<<BN_BLOCKS, dim3(128), 0, stream>>>(outg, ps, pss);
    bn_final_k<<<1, dim3(128), 0, stream>>>(ps, pss, gamma, beta, scsh);
    bn_apply_relu_k<<<zeroGrid, blk, 0, stream>>>(outg, scsh);

    // m2 = relu(hb@Wp2^T + bp2) (bf16)
    gemm_k<true, false, true, false><<<gemmGrid, blk, 0, stream>>>(
        outg, nullptr, Wp2, nullptr, bp2, nullptr, m2, NNODES);

    zero_k<<<zeroGrid, blk, 0, stream>>>((float4*)agg, (long)NNODES * FD / 4);
    scatter_max_k<<<scatGrid, blk, 0, stream>>>(m2, src, dst, (unsigned int*)agg, NEDGES);

    // out = hb@Ws2^T + agg2@Wn2^T + b2, in-place on outg (row r of C depends
    // only on row r of A0/A1 within the same wave -> in-place safe)
    gemm_k<false, false, false, true><<<gemmGrid, blk, 0, stream>>>(
        outg, agg, Ws2, Wn2, b2, nullptr, outg, NNODES);
  }
}

// Round 2
// 1432.458 us; speedup vs baseline: 3.5450x; 3.5450x over previous
//
#include <hip/hip_runtime.h>
#include <hip/hip_bf16.h>

#define NNODES 100000
#define FD 128
#define NEDGES 640000
#define BN_BLOCKS 512
#define NB 391  // (NNODES+255)/256

typedef __bf16 bf16x8 __attribute__((ext_vector_type(8)));
typedef float f32x4 __attribute__((ext_vector_type(4)));
typedef unsigned short u16x8 __attribute__((ext_vector_type(8)));

__device__ __forceinline__ bf16x8 cvt8(float4 a, float4 b) {
  bf16x8 r;
  r[0] = (__bf16)a.x; r[1] = (__bf16)a.y; r[2] = (__bf16)a.z; r[3] = (__bf16)a.w;
  r[4] = (__bf16)b.x; r[5] = (__bf16)b.y; r[6] = (__bf16)b.z; r[7] = (__bf16)b.w;
  return r;
}

// One K=128 pass of out += A @ W^T. A is f32 or bf16 [M][128]; W f32 [128][128].
template <bool ABF>
__device__ __forceinline__ void gemm_pass(const void* __restrict__ Av,
                                          const float* __restrict__ W,
                                          int rbase, int M, int lr, int lg,
                                          f32x4 (&acc)[2][8]) {
  // B fragments: lane holds n = c*16+lr, k = kk*32 + lg*8 .. +7
  bf16x8 bf[8][4];
#pragma unroll
  for (int c = 0; c < 8; ++c)
#pragma unroll
    for (int kk = 0; kk < 4; ++kk) {
      const float* p = W + (c * 16 + lr) * FD + kk * 32 + lg * 8;
      float4 x = *(const float4*)p;
      float4 y = *(const float4*)(p + 4);
      bf[c][kk] = cvt8(x, y);
    }
#pragma unroll
  for (int t = 0; t < 2; ++t) {
    int row = rbase + t * 16 + lr;
    if (row > M - 1) row = M - 1;  // clamp; stores guarded in epilogue
    const long boff = (long)row * FD + lg * 8;
#pragma unroll
    for (int kk = 0; kk < 4; ++kk) {
      bf16x8 af;
      if constexpr (ABF) {
        af = *(const bf16x8*)((const __bf16*)Av + boff + kk * 32);
      } else {
        const float* ap = (const float*)Av + boff + kk * 32;
        float4 x = *(const float4*)ap;
        float4 y = *(const float4*)(ap + 4);
        af = cvt8(x, y);
      }
#pragma unroll
      for (int c = 0; c < 8; ++c)
        acc[t][c] = __builtin_amdgcn_mfma_f32_16x16x32_bf16(af, bf[c][kk], acc[t][c], 0, 0, 0);
    }
  }
}

// out[M x 128] = A0 @ W0^T (+ A1 @ W1^T) + bias + addsrc, optional relu.
template <bool RELU, bool ADD, bool OUTBF16, bool A0BF16, bool TWOA>
__global__ __launch_bounds__(256, 2) void gemm_k(
    const void* __restrict__ A0, const void* __restrict__ A1,
    const float* __restrict__ W0, const float* __restrict__ W1,
    const float* __restrict__ bias, const float* __restrict__ addsrc,
    void* __restrict__ outp, int M) {
  const int wid = threadIdx.x >> 6;
  const int lane = threadIdx.x & 63;
  const int lr = lane & 15;
  const int lg = lane >> 4;

  for (int chunk = 0; chunk < 2; ++chunk) {
    const int rbase = blockIdx.x * 256 + chunk * 128 + wid * 32;
    if (rbase >= M) break;  // per-wave uniform, no barriers in kernel

    f32x4 acc[2][8];
#pragma unroll
    for (int t = 0; t < 2; ++t)
#pragma unroll
      for (int c = 0; c < 8; ++c) acc[t][c] = (f32x4){0.f, 0.f, 0.f, 0.f};

    gemm_pass<A0BF16>(A0, W0, rbase, M, lr, lg, acc);
    if constexpr (TWOA) gemm_pass<true>(A1, W1, rbase, M, lr, lg, acc);

    // D element (row = rbase + t*16 + lg*4 + j, col = c*16 + lr)
#pragma unroll
    for (int t = 0; t < 2; ++t)
#pragma unroll
      for (int j = 0; j < 4; ++j) {
        const int row = rbase + t * 16 + lg * 4 + j;
        if (row < M) {
#pragma unroll
          for (int c = 0; c < 8; ++c) {
            const int col = c * 16 + lr;
            float v = acc[t][c][j];
            if (bias) v += bias[col];
            if (ADD) v += addsrc[(long)row * FD + col];
            if (RELU) v = v > 0.f ? v : 0.f;
            if (OUTBF16)
              ((__bf16*)outp)[(long)row * FD + col] = (__bf16)v;
            else
              ((float*)outp)[(long)row * FD + col] = v;
          }
        }
      }
  }
}

// ---- counting-sort segment-max pipeline (no feature-space atomics) ----

__global__ __launch_bounds__(256) void hist_k(const int* __restrict__ dst,
                                              unsigned* __restrict__ deg) {
  const int e = blockIdx.x * 256 + threadIdx.x;
  if (e < NEDGES) atomicAdd(&deg[dst[e]], 1u);
}

__global__ __launch_bounds__(256) void blocksum_k(const unsigned* __restrict__ deg,
                                                  unsigned* __restrict__ bsum) {
  __shared__ unsigned s[256];
  const int i = blockIdx.x * 256 + threadIdx.x;
  s[threadIdx.x] = (i < NNODES) ? deg[i] : 0u;
  __syncthreads();
#pragma unroll
  for (int o = 128; o > 0; o >>= 1) {
    if (threadIdx.x < o) s[threadIdx.x] += s[threadIdx.x + o];
    __syncthreads();
  }
  if (threadIdx.x == 0) bsum[blockIdx.x] = s[0];
}

__global__ __launch_bounds__(512) void scanb_k(const unsigned* __restrict__ bsum,
                                               unsigned* __restrict__ boffs,
                                               unsigned* __restrict__ offs) {
  __shared__ unsigned s[512];
  const unsigned v = (threadIdx.x < NB) ? bsum[threadIdx.x] : 0u;
  s[threadIdx.x] = v;
  __syncthreads();
#pragma unroll
  for (int o = 1; o < 512; o <<= 1) {
    unsigned t = (threadIdx.x >= o) ? s[threadIdx.x - o] : 0u;
    __syncthreads();
    s[threadIdx.x] += t;
    __syncthreads();
  }
  if (threadIdx.x < NB) boffs[threadIdx.x] = s[threadIdx.x] - v;  // exclusive
  if (threadIdx.x == 0) offs[NNODES] = NEDGES;
}

__global__ __launch_bounds__(256) void offsets_k(const unsigned* __restrict__ deg,
                                                 const unsigned* __restrict__ boffs,
                                                 unsigned* __restrict__ offs,
                                                 unsigned* __restrict__ cursor) {
  __shared__ unsigned s[256];
  const int i = blockIdx.x * 256 + threadIdx.x;
  const unsigned v = (i < NNODES) ? deg[i] : 0u;
  s[threadIdx.x] = v;
  __syncthreads();
#pragma unroll
  for (int o = 1; o < 256; o <<= 1) {
    unsigned t = (threadIdx.x >= o) ? s[threadIdx.x - o] : 0u;
    __syncthreads();
    s[threadIdx.x] += t;
    __syncthreads();
  }
  const unsigned excl = s[threadIdx.x] - v + boffs[blockIdx.x];
  if (i < NNODES) {
    offs[i] = excl;
    cursor[i] = excl;
  }
}

__global__ __launch_bounds__(256) void esort_k(const int* __restrict__ src,
                                               const int* __restrict__ dst,
                                               unsigned* __restrict__ cursor,
                                               int* __restrict__ ssrc) {
  const int e = blockIdx.x * 256 + threadIdx.x;
  if (e < NEDGES) {
    const unsigned p = atomicAdd(&cursor[dst[e]], 1u);
    ssrc[p] = src[e];
  }
}

// 16 lanes per node; max over that node's in-edges. bf16 values are >= 0
// (post-relu) so unsigned 16-bit bit-compare == value compare; empty -> 0.
__global__ __launch_bounds__(256) void agg_k(const unsigned short* __restrict__ m,
                                             const int* __restrict__ ssrc,
                                             const unsigned* __restrict__ offs,
                                             unsigned short* __restrict__ agg) {
  const int gid = blockIdx.x * 256 + threadIdx.x;
  const int node = gid >> 4;
  if (node >= NNODES) return;
  const int fl = (gid & 15) * 8;
  const unsigned beg = offs[node], end = offs[node + 1];
  u16x8 acc = {0, 0, 0, 0, 0, 0, 0, 0};
  for (unsigned i = beg; i < end; ++i) {
    const int s = ssrc[i];
    const u16x8 v = *(const u16x8*)(m + (long)s * FD + fl);
#pragma unroll
    for (int j = 0; j < 8; ++j) acc[j] = v[j] > acc[j] ? v[j] : acc[j];
  }
  *(u16x8*)(agg + (long)node * FD + fl) = acc;
}

// ---- batchnorm ----

__global__ __launch_bounds__(128) void bn_partial_k(const float* __restrict__ h,
                                                    float* __restrict__ ps,
                                                    float* __restrict__ pss) {
  const int f = threadIdx.x;
  float s = 0.f, ss = 0.f;
  for (int r = blockIdx.x; r < NNODES; r += BN_BLOCKS) {
    float x = h[(long)r * FD + f];
    s += x;
    ss += x * x;
  }
  ps[blockIdx.x * FD + f] = s;
  pss[blockIdx.x * FD + f] = ss;
}

__global__ __launch_bounds__(128) void bn_final_k(const float* __restrict__ ps,
                                                  const float* __restrict__ pss,
                                                  const float* __restrict__ gamma,
                                                  const float* __restrict__ beta,
                                                  float* __restrict__ scsh) {
  const int f = threadIdx.x;
  float s = 0.f, ss = 0.f;
  for (int b = 0; b < BN_BLOCKS; ++b) {
    s += ps[b * FD + f];
    ss += pss[b * FD + f];
  }
  const float mu = s / (float)NNODES;
  const float var = ss / (float)NNODES - mu * mu;
  const float sc = rsqrtf(var + 1e-5f) * gamma[f];
  scsh[f] = sc;
  scsh[FD + f] = beta[f] - mu * sc;
}

__global__ __launch_bounds__(256) void bn_apply_relu_k(float* __restrict__ h,
                                                       const float* __restrict__ scsh) {
  const long base = ((long)blockIdx.x * 256 + threadIdx.x) * 4;
  if (base >= (long)NNODES * FD) return;
  const int f = (int)(base & (FD - 1));
  float4 x = *(float4*)(h + base);
  const float4 sc = *(const float4*)(scsh + f);
  const float4 sh = *(const float4*)(scsh + FD + f);
  float4 y;
  y.x = fmaxf(x.x * sc.x + sh.x, 0.f);
  y.y = fmaxf(x.y * sc.y + sh.y, 0.f);
  y.z = fmaxf(x.z * sc.z + sh.z, 0.f);
  y.w = fmaxf(x.w * sc.w + sh.w, 0.f);
  *(float4*)(h + base) = y;
}

__global__ __launch_bounds__(256) void zero_k(float4* __restrict__ p, long n4) {
  const long i = (long)blockIdx.x * 256 + threadIdx.x;
  if (i < n4) p[i] = (float4){0.f, 0.f, 0.f, 0.f};
}

extern "C" void kernel_launch(void* const* d_in, const int* in_sizes, int n_in,
                              void* d_out, int out_size, void* d_ws, size_t ws_size,
                              hipStream_t stream) {
  const float* feat = (const float*)d_in[0];
  const int* edges = (const int*)d_in[1];
  const float* Wp1 = (const float*)d_in[2];
  const float* bp1 = (const float*)d_in[3];
  const float* Ws1 = (const float*)d_in[4];
  const float* Wn1 = (const float*)d_in[5];
  const float* b1 = (const float*)d_in[6];
  const float* gamma = (const float*)d_in[7];
  const float* beta = (const float*)d_in[8];
  const float* Wp2 = (const float*)d_in[9];
  const float* bp2 = (const float*)d_in[10];
  const float* Ws2 = (const float*)d_in[11];
  const float* Wn2 = (const float*)d_in[12];
  const float* b2 = (const float*)d_in[13];

  // workspace layout (bytes)
  char* w = (char*)d_ws;
  __bf16* m1 = (__bf16*)w;                              // 25.6 MB
  float* hs1 = (float*)(w + 25600000);                  // 51.2 MB
  __bf16* aggb = (__bf16*)(w + 76800000);               // 25.6 MB bf16 agg
  __bf16* m2 = (__bf16*)(w + 102400000);                // 25.6 MB
  unsigned* deg = (unsigned*)(w + 128000000);           // 400 KB
  unsigned* offs = (unsigned*)(w + 128400128);          // 400 KB + 4
  unsigned* cursor = (unsigned*)(w + 128800512);        // 400 KB
  unsigned* bsum = (unsigned*)(w + 129200640);          // 2 KB
  unsigned* boffs = (unsigned*)(w + 129202688);         // 2 KB
  int* ssrc = (int*)(w + 129204736);                    // 2.56 MB
  float* ps = (float*)(w + 131765248);                  // 256 KB
  float* pss = (float*)(w + 132027392);                 // 256 KB
  float* scsh = (float*)(w + 132289536);                // 1 KB

  const dim3 blk(256);
  const int gemmGrid = (NNODES + 255) / 256;
  const int bnApplyGrid = (int)(((long)NNODES * FD / 4 + 255) / 256);
  const int edgeGrid = (NEDGES + 255) / 256;
  const int aggGrid = (NNODES * 16 + 255) / 256;
  const int degZeroGrid = (NNODES * 4 / 16 + 255) / 256;  // 25000 float4s

  // graph-independent: m1 = relu(feat@Wp1^T + bp1), hs1 = feat@Ws1^T + b1
  gemm_k<true, false, true, false, false><<<gemmGrid, blk, 0, stream>>>(
      feat, nullptr, Wp1, nullptr, bp1, nullptr, m1, NNODES);
  gemm_k<false, false, false, false, false><<<gemmGrid, blk, 0, stream>>>(
      feat, nullptr, Ws1, nullptr, b1, nullptr, hs1, NNODES);

  for (int g = 0; g < 3; ++g) {
    const int* src = edges + (long)g * 2 * NEDGES;
    const int* dst = src + NEDGES;
    float* outg = (float*)d_out + (long)g * NNODES * FD;

    // bucket edges by dst (counting sort) — shared by both layers
    zero_k<<<degZeroGrid, blk, 0, stream>>>((float4*)deg, NNODES / 4);
    hist_k<<<edgeGrid, blk, 0, stream>>>(dst, deg);
    blocksum_k<<<NB, blk, 0, stream>>>(deg, bsum);
    scanb_k<<<1, dim3(512), 0, stream>>>(bsum, boffs, offs);
    offsets_k<<<NB, blk, 0, stream>>>(deg, boffs, offs, cursor);
    esort_k<<<edgeGrid, blk, 0, stream>>>(src, dst, cursor, ssrc);

    // layer-1 aggregate + combine
    agg_k<<<aggGrid, blk, 0, stream>>>((const unsigned short*)m1, ssrc, offs,
                                       (unsigned short*)aggb);
    gemm_k<false, true, false, true, false><<<gemmGrid, blk, 0, stream>>>(
        aggb, nullptr, Wn1, nullptr, nullptr, hs1, outg, NNODES);

    bn_partial_k<<<BN_BLOCKS, dim3(128), 0, stream>>>(outg, ps, pss);
    bn_final_k<<<1, dim3(128), 0, stream>>>(ps, pss, gamma, beta, scsh);
    bn_apply_relu_k<<<bnApplyGrid, blk, 0, stream>>>(outg, scsh);

    // layer 2
    gemm_k<true, false, true, false, false><<<gemmGrid, blk, 0, stream>>>(
        outg, nullptr, Wp2, nullptr, bp2, nullptr, m2, NNODES);
    agg_k<<<aggGrid, blk, 0, stream>>>((const unsigned short*)m2, ssrc, offs,
                                       (unsigned short*)aggb);
    // out = hb@Ws2^T + agg2@Wn2^T + b2, in-place on outg (row r of C depends
    // only on row r of A0/A1 within the same wave -> in-place safe)
    gemm_k<false, false, false, false, true><<<gemmGrid, blk, 0, stream>>>(
        outg, aggb, Ws2, Wn2, b2, nullptr, outg, NNODES);
  }
}

// Round 3
// 1156.420 us; speedup vs baseline: 4.3912x; 1.2387x over previous
//
#include <hip/hip_runtime.h>
#include <hip/hip_bf16.h>

#define NNODES 100000
#define FD 128
#define NEDGES 640000
#define NB 391            // ceil(NNODES/256)
#define GEMM_GRID 782     // ceil(NNODES/128)
#define OFFS_U32 100032   // padded NNODES+1

typedef __bf16 bf16x8 __attribute__((ext_vector_type(8)));
typedef float f32x4 __attribute__((ext_vector_type(4)));
typedef unsigned short u16x8 __attribute__((ext_vector_type(8)));

__device__ __forceinline__ bf16x8 cvt8(float4 a, float4 b) {
  bf16x8 r;
  r[0] = (__bf16)a.x; r[1] = (__bf16)a.y; r[2] = (__bf16)a.z; r[3] = (__bf16)a.w;
  r[4] = (__bf16)b.x; r[5] = (__bf16)b.y; r[6] = (__bf16)b.z; r[7] = (__bf16)b.w;
  return r;
}

// A-fragment loader. AMODE: 0 = f32, 1 = bf16, 2 = f32 with fused BN+relu
// (a = max(h*sc[k]+sh[k], 0); scsh[0..127]=sc, [128..255]=sh, L1-hot).
template <int AMODE>
__device__ __forceinline__ bf16x8 load_afrag(const void* __restrict__ A, long row,
                                             int k, const float* __restrict__ scsh) {
  if constexpr (AMODE == 1) {
    return *(const bf16x8*)((const __bf16*)A + row * FD + k);
  } else {
    const float* ap = (const float*)A + row * FD + k;
    float4 x = *(const float4*)ap;
    float4 y = *(const float4*)(ap + 4);
    if constexpr (AMODE == 2) {
      const float4 scx = *(const float4*)(scsh + k);
      const float4 scy = *(const float4*)(scsh + k + 4);
      const float4 shx = *(const float4*)(scsh + 128 + k);
      const float4 shy = *(const float4*)(scsh + 128 + k + 4);
      x.x = fmaxf(x.x * scx.x + shx.x, 0.f);
      x.y = fmaxf(x.y * scx.y + shx.y, 0.f);
      x.z = fmaxf(x.z * scx.z + shx.z, 0.f);
      x.w = fmaxf(x.w * scx.w + shx.w, 0.f);
      y.x = fmaxf(y.x * scy.x + shy.x, 0.f);
      y.y = fmaxf(y.y * scy.y + shy.y, 0.f);
      y.z = fmaxf(y.z * scy.z + shy.z, 0.f);
      y.w = fmaxf(y.w * scy.w + shy.w, 0.f);
    }
    return cvt8(x, y);
  }
}

// out[M x 128] = f(A0) @ W0^T (+ A1 @ W1^T) + bias + addsrc(bf16), opt relu.
// Each wave: 32 rows x 128 cols; block 128 rows; grid GEMM_GRID.
// A-frags resident (32 VGPR); W streamed per 16-col block (16 VGPR live).
// STATS: per-block column sum/sumsq of the (pre-relu) output -> pblk.
template <int AMODE, bool TWOA, bool RELU, bool OUTBF16, bool ADD, bool STATS>
__global__ __launch_bounds__(256, 3) void gemm_k(
    const void* __restrict__ A0, const __bf16* __restrict__ A1,
    const float* __restrict__ W0, const float* __restrict__ W1,
    const float* __restrict__ bias, const __bf16* __restrict__ addsrc,
    const float* __restrict__ scsh, void* __restrict__ outp,
    float* __restrict__ pblk, int M) {
  const int wid = threadIdx.x >> 6;
  const int lane = threadIdx.x & 63;
  const int lr = lane & 15;
  const int lg = lane >> 4;
  const int kbase = lg * 8;
  const int rbase = blockIdx.x * 128 + wid * 32;
  __shared__ float s_red[2][4][128];

  if constexpr (!STATS) {
    if (rbase >= M) return;  // wave-uniform; no barriers in non-STATS path
  }

  f32x4 acc[2][8];
#pragma unroll
  for (int t = 0; t < 2; ++t)
#pragma unroll
    for (int c = 0; c < 8; ++c) acc[t][c] = (f32x4){0.f, 0.f, 0.f, 0.f};

  {
    bf16x8 af[2][4];
#pragma unroll
    for (int t = 0; t < 2; ++t) {
      long row = rbase + t * 16 + lr;
      if (row > M - 1) row = M - 1;  // clamp; stores guarded below
#pragma unroll
      for (int kk = 0; kk < 4; ++kk)
        af[t][kk] = load_afrag<AMODE>(A0, row, kk * 32 + kbase, scsh);
    }
#pragma unroll
    for (int c = 0; c < 8; ++c) {
      bf16x8 bw[4];
#pragma unroll
      for (int kk = 0; kk < 4; ++kk) {
        const float* p = W0 + (c * 16 + lr) * FD + kk * 32 + kbase;
        bw[kk] = cvt8(*(const float4*)p, *(const float4*)(p + 4));
      }
#pragma unroll
      for (int t = 0; t < 2; ++t)
#pragma unroll
        for (int kk = 0; kk < 4; ++kk)
          acc[t][c] = __builtin_amdgcn_mfma_f32_16x16x32_bf16(af[t][kk], bw[kk], acc[t][c], 0, 0, 0);
    }
  }
  if constexpr (TWOA) {
    bf16x8 af[2][4];
#pragma unroll
    for (int t = 0; t < 2; ++t) {
      long row = rbase + t * 16 + lr;
      if (row > M - 1) row = M - 1;
#pragma unroll
      for (int kk = 0; kk < 4; ++kk)
        af[t][kk] = load_afrag<1>(A1, row, kk * 32 + kbase, nullptr);
    }
#pragma unroll
    for (int c = 0; c < 8; ++c) {
      bf16x8 bw[4];
#pragma unroll
      for (int kk = 0; kk < 4; ++kk) {
        const float* p = W1 + (c * 16 + lr) * FD + kk * 32 + kbase;
        bw[kk] = cvt8(*(const float4*)p, *(const float4*)(p + 4));
      }
#pragma unroll
      for (int t = 0; t < 2; ++t)
#pragma unroll
        for (int kk = 0; kk < 4; ++kk)
          acc[t][c] = __builtin_amdgcn_mfma_f32_16x16x32_bf16(af[t][kk], bw[kk], acc[t][c], 0, 0, 0);
    }
  }

  // epilogue: D(row = rbase + t*16 + lg*4 + j, col = c*16 + lr)
  float ps[8], pss[8];
#pragma unroll
  for (int c = 0; c < 8; ++c) { ps[c] = 0.f; pss[c] = 0.f; }

#pragma unroll
  for (int t = 0; t < 2; ++t)
#pragma unroll
    for (int j = 0; j < 4; ++j) {
      const int row = rbase + t * 16 + lg * 4 + j;
      if (row < M) {
#pragma unroll
        for (int c = 0; c < 8; ++c) {
          const int col = c * 16 + lr;
          float v = acc[t][c][j];
          if (bias) v += bias[col];
          if constexpr (ADD) v += (float)addsrc[(long)row * FD + col];
          if constexpr (STATS) { ps[c] += v; pss[c] += v * v; }
          if constexpr (RELU) v = fmaxf(v, 0.f);
          if constexpr (OUTBF16)
            ((__bf16*)outp)[(long)row * FD + col] = (__bf16)v;
          else
            ((float*)outp)[(long)row * FD + col] = v;
        }
      }
    }

  if constexpr (STATS) {
#pragma unroll
    for (int c = 0; c < 8; ++c) {
      float s = ps[c], ss = pss[c];
      s += __shfl_xor(s, 16); s += __shfl_xor(s, 32);
      ss += __shfl_xor(ss, 16); ss += __shfl_xor(ss, 32);
      if (lane < 16) {
        s_red[0][wid][c * 16 + lr] = s;
        s_red[1][wid][c * 16 + lr] = ss;
      }
    }
    __syncthreads();
    const int tid = threadIdx.x;
    const int which = tid >> 7, col = tid & 127;
    pblk[(long)blockIdx.x * 256 + tid] =
        s_red[which][0][col] + s_red[which][1][col] + s_red[which][2][col] + s_red[which][3][col];
  }
}

// reduce per-block BN partials -> scale/shift
__global__ __launch_bounds__(256) void bn_final2_k(const float* __restrict__ pblk,
                                                   const float* __restrict__ gamma,
                                                   const float* __restrict__ beta,
                                                   float* __restrict__ scsh) {
  __shared__ float s_ss[128];
  const int tid = threadIdx.x;
  float a0 = 0.f, a1 = 0.f, a2 = 0.f, a3 = 0.f;
  int r = 0;
  for (; r + 4 <= GEMM_GRID; r += 4) {
    a0 += pblk[(long)(r + 0) * 256 + tid];
    a1 += pblk[(long)(r + 1) * 256 + tid];
    a2 += pblk[(long)(r + 2) * 256 + tid];
    a3 += pblk[(long)(r + 3) * 256 + tid];
  }
  for (; r < GEMM_GRID; ++r) a0 += pblk[(long)r * 256 + tid];
  const float tot = a0 + a1 + a2 + a3;
  if (tid >= 128) s_ss[tid - 128] = tot;
  __syncthreads();
  if (tid < 128) {
    const float mu = tot / (float)NNODES;
    const float var = s_ss[tid] / (float)NNODES - mu * mu;
    const float sc = rsqrtf(var + 1e-5f) * gamma[tid];
    scsh[tid] = sc;
    scsh[128 + tid] = beta[tid] - mu * sc;
  }
}

// ---- batched (3-graph) counting-sort pipeline ----

__global__ __launch_bounds__(256) void hist3_k(const int* __restrict__ edges,
                                               unsigned* __restrict__ deg3) {
  const int g = blockIdx.y;
  const int e = blockIdx.x * 256 + threadIdx.x;
  if (e < NEDGES)
    atomicAdd(&deg3[(long)g * NNODES + edges[(long)g * 2 * NEDGES + NEDGES + e]], 1u);
}

__global__ __launch_bounds__(256) void blocksum3_k(const unsigned* __restrict__ deg3,
                                                   unsigned* __restrict__ bsum3) {
  __shared__ unsigned s[256];
  const int g = blockIdx.y;
  const int i = blockIdx.x * 256 + threadIdx.x;
  s[threadIdx.x] = (i < NNODES) ? deg3[(long)g * NNODES + i] : 0u;
  __syncthreads();
#pragma unroll
  for (int o = 128; o > 0; o >>= 1) {
    if (threadIdx.x < o) s[threadIdx.x] += s[threadIdx.x + o];
    __syncthreads();
  }
  if (threadIdx.x == 0) bsum3[g * NB + blockIdx.x] = s[0];
}

__global__ __launch_bounds__(512) void scanb3_k(const unsigned* __restrict__ bsum3,
                                                unsigned* __restrict__ boffs3,
                                                unsigned* __restrict__ offs3) {
  __shared__ unsigned s[512];
  const int g = blockIdx.y;
  const unsigned v = (threadIdx.x < NB) ? bsum3[g * NB + threadIdx.x] : 0u;
  s[threadIdx.x] = v;
  __syncthreads();
#pragma unroll
  for (int o = 1; o < 512; o <<= 1) {
    unsigned t = (threadIdx.x >= o) ? s[threadIdx.x - o] : 0u;
    __syncthreads();
    s[threadIdx.x] += t;
    __syncthreads();
  }
  if (threadIdx.x < NB) boffs3[g * NB + threadIdx.x] = s[threadIdx.x] - v;
  if (threadIdx.x == 0) offs3[(long)g * OFFS_U32 + NNODES] = NEDGES;
}

__global__ __launch_bounds__(256) void offsets3_k(const unsigned* __restrict__ deg3,
                                                  const unsigned* __restrict__ boffs3,
                                                  unsigned* __restrict__ offs3,
                                                  unsigned* __restrict__ cursor3) {
  __shared__ unsigned s[256];
  const int g = blockIdx.y;
  const int i = blockIdx.x * 256 + threadIdx.x;
  const unsigned v = (i < NNODES) ? deg3[(long)g * NNODES + i] : 0u;
  s[threadIdx.x] = v;
  __syncthreads();
#pragma unroll
  for (int o = 1; o < 256; o <<= 1) {
    unsigned t = (threadIdx.x >= o) ? s[threadIdx.x - o] : 0u;
    __syncthreads();
    s[threadIdx.x] += t;
    __syncthreads();
  }
  const unsigned excl = s[threadIdx.x] - v + boffs3[g * NB + blockIdx.x];
  if (i < NNODES) {
    offs3[(long)g * OFFS_U32 + i] = excl;
    cursor3[(long)g * NNODES + i] = excl;
  }
}

__global__ __launch_bounds__(256) void esort3_k(const int* __restrict__ edges,
                                                unsigned* __restrict__ cursor3,
                                                int* __restrict__ ssrc3) {
  const int g = blockIdx.y;
  const int e = blockIdx.x * 256 + threadIdx.x;
  if (e < NEDGES) {
    const int s = edges[(long)g * 2 * NEDGES + e];
    const int d = edges[(long)g * 2 * NEDGES + NEDGES + e];
    const unsigned p = atomicAdd(&cursor3[(long)g * NNODES + d], 1u);
    ssrc3[(long)g * NEDGES + p] = s;
  }
}

// 16 lanes per node; max over in-edges (bf16 >= 0 -> u16 bit-compare exact).
__global__ __launch_bounds__(256) void agg_k(const unsigned short* __restrict__ m,
                                             const int* __restrict__ ssrc,
                                             const unsigned* __restrict__ offs,
                                             unsigned short* __restrict__ agg) {
  const int gid = blockIdx.x * 256 + threadIdx.x;
  const int node = gid >> 4;
  if (node >= NNODES) return;
  const int fl = (gid & 15) * 8;
  const unsigned beg = offs[node], end = offs[node + 1];
  u16x8 acc = {0, 0, 0, 0, 0, 0, 0, 0};
  for (unsigned i = beg; i < end; ++i) {
    const int s = ssrc[i];
    const u16x8 v = *(const u16x8*)(m + (long)s * FD + fl);
#pragma unroll
    for (int j = 0; j < 8; ++j) acc[j] = v[j] > acc[j] ? v[j] : acc[j];
  }
  *(u16x8*)(agg + (long)node * FD + fl) = acc;
}

__global__ __launch_bounds__(256) void zero_k(float4* __restrict__ p, long n4) {
  const long i = (long)blockIdx.x * 256 + threadIdx.x;
  if (i < n4) p[i] = (float4){0.f, 0.f, 0.f, 0.f};
}

extern "C" void kernel_launch(void* const* d_in, const int* in_sizes, int n_in,
                              void* d_out, int out_size, void* d_ws, size_t ws_size,
                              hipStream_t stream) {
  const float* feat = (const float*)d_in[0];
  const int* edges = (const int*)d_in[1];
  const float* Wp1 = (const float*)d_in[2];
  const float* bp1 = (const float*)d_in[3];
  const float* Ws1 = (const float*)d_in[4];
  const float* Wn1 = (const float*)d_in[5];
  const float* b1 = (const float*)d_in[6];
  const float* gamma = (const float*)d_in[7];
  const float* beta = (const float*)d_in[8];
  const float* Wp2 = (const float*)d_in[9];
  const float* bp2 = (const float*)d_in[10];
  const float* Ws2 = (const float*)d_in[11];
  const float* Wn2 = (const float*)d_in[12];
  const float* b2 = (const float*)d_in[13];

  // workspace layout (bytes, 256B-aligned); total ~114.5 MB
  char* w = (char*)d_ws;
  __bf16* m1 = (__bf16*)w;                         // 25.6 MB
  __bf16* hs1b = (__bf16*)(w + 25600000);          // 25.6 MB
  __bf16* aggb = (__bf16*)(w + 51200000);          // 25.6 MB
  __bf16* m2 = (__bf16*)(w + 76800000);            // 25.6 MB
  unsigned* deg3 = (unsigned*)(w + 102400000);     // 1.2 MB
  unsigned* offs3 = (unsigned*)(w + 103600000);    // 1.2 MB
  unsigned* cursor3 = (unsigned*)(w + 104800384);  // 1.2 MB
  unsigned* bsum3 = (unsigned*)(w + 106000384);    // 8 KB
  unsigned* boffs3 = (unsigned*)(w + 106008576);   // 8 KB
  int* ssrc3 = (int*)(w + 106016768);              // 7.68 MB
  float* pblk = (float*)(w + 113696768);           // 800 KB
  float* scsh = (float*)(w + 114497536);           // 1 KB

  const dim3 blk(256);
  const int edgeGrid = (NEDGES + 255) / 256;           // 2500
  const int aggGrid = (NNODES * 16 + 255) / 256;       // 6250
  const int degZeroGrid = (3 * NNODES / 4 + 255) / 256;

  // batched edge sort for all 3 graphs
  zero_k<<<degZeroGrid, blk, 0, stream>>>((float4*)deg3, 3L * NNODES / 4);
  hist3_k<<<dim3(edgeGrid, 3), blk, 0, stream>>>(edges, deg3);
  blocksum3_k<<<dim3(NB, 3), blk, 0, stream>>>(deg3, bsum3);
  scanb3_k<<<dim3(1, 3), dim3(512), 0, stream>>>(bsum3, boffs3, offs3);
  offsets3_k<<<dim3(NB, 3), blk, 0, stream>>>(deg3, boffs3, offs3, cursor3);
  esort3_k<<<dim3(edgeGrid, 3), blk, 0, stream>>>(edges, cursor3, ssrc3);

  // graph-independent heads
  gemm_k<0, false, true, true, false, false><<<GEMM_GRID, blk, 0, stream>>>(
      feat, nullptr, Wp1, nullptr, bp1, nullptr, nullptr, m1, nullptr, NNODES);
  gemm_k<0, false, false, true, false, false><<<GEMM_GRID, blk, 0, stream>>>(
      feat, nullptr, Ws1, nullptr, b1, nullptr, nullptr, hs1b, nullptr, NNODES);

  for (int g = 0; g < 3; ++g) {
    const unsigned* offs = offs3 + (long)g * OFFS_U32;
    const int* ssrc = ssrc3 + (long)g * NEDGES;
    float* outg = (float*)d_out + (long)g * NNODES * FD;

    // layer 1: h = hs1 + agg@Wn1^T  (f32 -> outg) + fused BN stats
    agg_k<<<aggGrid, blk, 0, stream>>>((const unsigned short*)m1, ssrc, offs,
                                       (unsigned short*)aggb);
    gemm_k<1, false, false, false, true, true><<<GEMM_GRID, blk, 0, stream>>>(
        aggb, nullptr, Wn1, nullptr, nullptr, hs1b, nullptr, outg, pblk, NNODES);
    bn_final2_k<<<1, blk, 0, stream>>>(pblk, gamma, beta, scsh);

    // layer 2 (BN+relu fused into A-loads)
    gemm_k<2, false, true, true, false, false><<<GEMM_GRID, blk, 0, stream>>>(
        outg, nullptr, Wp2, nullptr, bp2, nullptr, scsh, m2, nullptr, NNODES);
    agg_k<<<aggGrid, blk, 0, stream>>>((const unsigned short*)m2, ssrc, offs,
                                       (unsigned short*)aggb);
    gemm_k<2, true, false, false, false, false><<<GEMM_GRID, blk, 0, stream>>>(
        outg, aggb, Ws2, Wn2, b2, nullptr, scsh, outg, nullptr, NNODES);
  }
}

// Round 4
// 1029.874 us; speedup vs baseline: 4.9308x; 1.1229x over previous
//
#include <hip/hip_runtime.h>
#include <hip/hip_bf16.h>

#define NNODES 100000
#define FD 128
#define NEDGES 640000
#define NB 391            // ceil(NNODES/256)
#define GEMM_GRID 782     // ceil(NNODES/128)
#define OFFS_U32 100032   // padded NNODES+1

typedef __bf16 bf16x8 __attribute__((ext_vector_type(8)));
typedef float f32x4 __attribute__((ext_vector_type(4)));
typedef unsigned short u16x8 __attribute__((ext_vector_type(8)));

__device__ __forceinline__ bf16x8 cvt8(float4 a, float4 b) {
  bf16x8 r;
  r[0] = (__bf16)a.x; r[1] = (__bf16)a.y; r[2] = (__bf16)a.z; r[3] = (__bf16)a.w;
  r[4] = (__bf16)b.x; r[5] = (__bf16)b.y; r[6] = (__bf16)b.z; r[7] = (__bf16)b.w;
  return r;
}

// A-row fragment loader: 4 x bf16x8 covering cols {kbase + kk*32 .. +8}.
// AM: 0 = f32, 1 = bf16, 3 = bf16 with fused BN+relu (scsh[0:128]=sc,
// [128:256]=sh), 4 = on-the-fly segment-max gather from m (bf16>=0 so u16
// bit-compare is exact; empty segment -> 0).
template <int AM>
__device__ __forceinline__ void load_arow(const void* __restrict__ A, long row,
                                          int kbase, const float* __restrict__ scsh,
                                          const int* __restrict__ ssrc,
                                          const unsigned* __restrict__ offs,
                                          bf16x8 (&af)[4]) {
  if constexpr (AM == 4) {
    const unsigned beg = offs[row];
    const unsigned end = offs[row + 1];
    u16x8 a0 = {0, 0, 0, 0, 0, 0, 0, 0}, a1 = a0, a2 = a0, a3 = a0;
    const unsigned short* m = (const unsigned short*)A;
    for (unsigned i = beg; i < end; ++i) {
      const unsigned short* mp = m + (long)ssrc[i] * FD + kbase;
      const u16x8 v0 = *(const u16x8*)(mp);
      const u16x8 v1 = *(const u16x8*)(mp + 32);
      const u16x8 v2 = *(const u16x8*)(mp + 64);
      const u16x8 v3 = *(const u16x8*)(mp + 96);
#pragma unroll
      for (int j = 0; j < 8; ++j) {
        a0[j] = v0[j] > a0[j] ? v0[j] : a0[j];
        a1[j] = v1[j] > a1[j] ? v1[j] : a1[j];
        a2[j] = v2[j] > a2[j] ? v2[j] : a2[j];
        a3[j] = v3[j] > a3[j] ? v3[j] : a3[j];
      }
    }
    af[0] = __builtin_bit_cast(bf16x8, a0);
    af[1] = __builtin_bit_cast(bf16x8, a1);
    af[2] = __builtin_bit_cast(bf16x8, a2);
    af[3] = __builtin_bit_cast(bf16x8, a3);
  } else if constexpr (AM == 1) {
#pragma unroll
    for (int kk = 0; kk < 4; ++kk)
      af[kk] = *(const bf16x8*)((const __bf16*)A + row * FD + kbase + kk * 32);
  } else if constexpr (AM == 3) {
#pragma unroll
    for (int kk = 0; kk < 4; ++kk) {
      const int k = kbase + kk * 32;
      const bf16x8 r = *(const bf16x8*)((const __bf16*)A + row * FD + k);
      const float4 scx = *(const float4*)(scsh + k);
      const float4 scy = *(const float4*)(scsh + k + 4);
      const float4 shx = *(const float4*)(scsh + 128 + k);
      const float4 shy = *(const float4*)(scsh + 128 + k + 4);
      bf16x8 o;
      o[0] = (__bf16)fmaxf((float)r[0] * scx.x + shx.x, 0.f);
      o[1] = (__bf16)fmaxf((float)r[1] * scx.y + shx.y, 0.f);
      o[2] = (__bf16)fmaxf((float)r[2] * scx.z + shx.z, 0.f);
      o[3] = (__bf16)fmaxf((float)r[3] * scx.w + shx.w, 0.f);
      o[4] = (__bf16)fmaxf((float)r[4] * scy.x + shy.x, 0.f);
      o[5] = (__bf16)fmaxf((float)r[5] * scy.y + shy.y, 0.f);
      o[6] = (__bf16)fmaxf((float)r[6] * scy.z + shy.z, 0.f);
      o[7] = (__bf16)fmaxf((float)r[7] * scy.w + shy.w, 0.f);
      af[kk] = o;
    }
  } else {  // AM == 0: f32
#pragma unroll
    for (int kk = 0; kk < 4; ++kk) {
      const int k = kbase + kk * 32;
      const float* ap = (const float*)A + row * FD + k;
      af[kk] = cvt8(*(const float4*)ap, *(const float4*)(ap + 4));
    }
  }
}

// One K=128 pass of acc += f(A) @ W^T for the wave's 32 rows x 128 cols.
template <int AM>
__device__ __forceinline__ void mma_pass(const void* __restrict__ A,
                                         const float* __restrict__ W,
                                         const float* __restrict__ scsh,
                                         const int* __restrict__ ssrc,
                                         const unsigned* __restrict__ offs,
                                         int rbase, int M, int lr, int lg,
                                         f32x4 (&acc)[2][8]) {
  const int kbase = lg * 8;
  bf16x8 af[2][4];
#pragma unroll
  for (int t = 0; t < 2; ++t) {
    long row = rbase + t * 16 + lr;
    if (row > M - 1) row = M - 1;  // clamp; stores guarded in epilogue
    load_arow<AM>(A, row, kbase, scsh, ssrc, offs, af[t]);
  }
#pragma unroll
  for (int c = 0; c < 8; ++c) {
    bf16x8 bw[4];
#pragma unroll
    for (int kk = 0; kk < 4; ++kk) {
      const float* p = W + (c * 16 + lr) * FD + kk * 32 + kbase;
      bw[kk] = cvt8(*(const float4*)p, *(const float4*)(p + 4));
    }
#pragma unroll
    for (int t = 0; t < 2; ++t)
#pragma unroll
      for (int kk = 0; kk < 4; ++kk)
        acc[t][c] = __builtin_amdgcn_mfma_f32_16x16x32_bf16(af[t][kk], bw[kk], acc[t][c], 0, 0, 0);
  }
}

// out[M x 128] = f(A0) @ W0^T (+ f(A1) @ W1^T) + bias + addsrc(bf16), opt relu.
// STATS: per-block column sum/sumsq of the pre-relu output -> pblk.
template <int A0M, int A1M, bool TWOA, bool RELU, bool OUTBF16, bool ADD, bool STATS>
__global__ __launch_bounds__(256, 3) void gemm_k(
    const void* __restrict__ A0, const void* __restrict__ A1,
    const float* __restrict__ W0, const float* __restrict__ W1,
    const float* __restrict__ bias, const __bf16* __restrict__ addsrc,
    const float* __restrict__ scsh, const int* __restrict__ ssrc,
    const unsigned* __restrict__ offs, void* __restrict__ outp,
    float* __restrict__ pblk, int M) {
  const int wid = threadIdx.x >> 6;
  const int lane = threadIdx.x & 63;
  const int lr = lane & 15;
  const int lg = lane >> 4;
  const int rbase = blockIdx.x * 128 + wid * 32;
  __shared__ float s_red[2][4][128];

  if constexpr (!STATS) {
    if (rbase >= M) return;  // wave-uniform; no barriers in this path
  }

  f32x4 acc[2][8];
#pragma unroll
  for (int t = 0; t < 2; ++t)
#pragma unroll
    for (int c = 0; c < 8; ++c) acc[t][c] = (f32x4){0.f, 0.f, 0.f, 0.f};

  mma_pass<A0M>(A0, W0, scsh, ssrc, offs, rbase, M, lr, lg, acc);
  if constexpr (TWOA) mma_pass<A1M>(A1, W1, scsh, ssrc, offs, rbase, M, lr, lg, acc);

  // epilogue: D(row = rbase + t*16 + lg*4 + j, col = c*16 + lr)
  float ps[8], pss[8];
#pragma unroll
  for (int c = 0; c < 8; ++c) { ps[c] = 0.f; pss[c] = 0.f; }

#pragma unroll
  for (int t = 0; t < 2; ++t)
#pragma unroll
    for (int j = 0; j < 4; ++j) {
      const int row = rbase + t * 16 + lg * 4 + j;
      if (row < M) {
#pragma unroll
        for (int c = 0; c < 8; ++c) {
          const int col = c * 16 + lr;
          float v = acc[t][c][j];
          if (bias) v += bias[col];
          if constexpr (ADD) v += (float)addsrc[(long)row * FD + col];
          if constexpr (STATS) { ps[c] += v; pss[c] += v * v; }
          if constexpr (RELU) v = fmaxf(v, 0.f);
          if constexpr (OUTBF16)
            ((__bf16*)outp)[(long)row * FD + col] = (__bf16)v;
          else
            ((float*)outp)[(long)row * FD + col] = v;
        }
      }
    }

  if constexpr (STATS) {
#pragma unroll
    for (int c = 0; c < 8; ++c) {
      float s = ps[c], ss = pss[c];
      s += __shfl_xor(s, 16); s += __shfl_xor(s, 32);
      ss += __shfl_xor(ss, 16); ss += __shfl_xor(ss, 32);
      if (lane < 16) {
        s_red[0][wid][c * 16 + lr] = s;
        s_red[1][wid][c * 16 + lr] = ss;
      }
    }
    __syncthreads();
    const int tid = threadIdx.x;
    const int which = tid >> 7, col = tid & 127;
    pblk[(long)blockIdx.x * 256 + tid] =
        s_red[which][0][col] + s_red[which][1][col] + s_red[which][2][col] + s_red[which][3][col];
  }
}

// reduce per-block BN partials -> scale/shift
__global__ __launch_bounds__(256) void bn_final2_k(const float* __restrict__ pblk,
                                                   const float* __restrict__ gamma,
                                                   const float* __restrict__ beta,
                                                   float* __restrict__ scsh) {
  __shared__ float s_ss[128];
  const int tid = threadIdx.x;
  float a0 = 0.f, a1 = 0.f, a2 = 0.f, a3 = 0.f;
  int r = 0;
  for (; r + 4 <= GEMM_GRID; r += 4) {
    a0 += pblk[(long)(r + 0) * 256 + tid];
    a1 += pblk[(long)(r + 1) * 256 + tid];
    a2 += pblk[(long)(r + 2) * 256 + tid];
    a3 += pblk[(long)(r + 3) * 256 + tid];
  }
  for (; r < GEMM_GRID; ++r) a0 += pblk[(long)r * 256 + tid];
  const float tot = a0 + a1 + a2 + a3;
  if (tid >= 128) s_ss[tid - 128] = tot;
  __syncthreads();
  if (tid < 128) {
    const float mu = tot / (float)NNODES;
    const float var = s_ss[tid] / (float)NNODES - mu * mu;
    const float sc = rsqrtf(var + 1e-5f) * gamma[tid];
    scsh[tid] = sc;
    scsh[128 + tid] = beta[tid] - mu * sc;
  }
}

// ---- batched (3-graph) counting-sort, rank-trick (atomics only in hist) ----

__global__ __launch_bounds__(256) void hist_rank3_k(const int* __restrict__ edges,
                                                    unsigned* __restrict__ deg3,
                                                    unsigned short* __restrict__ rank3) {
  const int g = blockIdx.y;
  const int e = blockIdx.x * 256 + threadIdx.x;
  if (e < NEDGES) {
    const int d = edges[(long)g * 2 * NEDGES + NEDGES + e];
    const unsigned r = atomicAdd(&deg3[(long)g * NNODES + d], 1u);
    rank3[(long)g * NEDGES + e] = (unsigned short)r;
  }
}

__global__ __launch_bounds__(256) void blocksum3_k(const unsigned* __restrict__ deg3,
                                                   unsigned* __restrict__ bsum3) {
  __shared__ unsigned s[256];
  const int g = blockIdx.y;
  const int i = blockIdx.x * 256 + threadIdx.x;
  s[threadIdx.x] = (i < NNODES) ? deg3[(long)g * NNODES + i] : 0u;
  __syncthreads();
#pragma unroll
  for (int o = 128; o > 0; o >>= 1) {
    if (threadIdx.x < o) s[threadIdx.x] += s[threadIdx.x + o];
    __syncthreads();
  }
  if (threadIdx.x == 0) bsum3[g * NB + blockIdx.x] = s[0];
}

__global__ __launch_bounds__(512) void scanb3_k(const unsigned* __restrict__ bsum3,
                                                unsigned* __restrict__ boffs3,
                                                unsigned* __restrict__ offs3) {
  __shared__ unsigned s[512];
  const int g = blockIdx.y;
  const unsigned v = (threadIdx.x < NB) ? bsum3[g * NB + threadIdx.x] : 0u;
  s[threadIdx.x] = v;
  __syncthreads();
#pragma unroll
  for (int o = 1; o < 512; o <<= 1) {
    unsigned t = (threadIdx.x >= o) ? s[threadIdx.x - o] : 0u;
    __syncthreads();
    s[threadIdx.x] += t;
    __syncthreads();
  }
  if (threadIdx.x < NB) boffs3[g * NB + threadIdx.x] = s[threadIdx.x] - v;
  if (threadIdx.x == 0) offs3[(long)g * OFFS_U32 + NNODES] = NEDGES;
}

__global__ __launch_bounds__(256) void offsets3_k(const unsigned* __restrict__ deg3,
                                                  const unsigned* __restrict__ boffs3,
                                                  unsigned* __restrict__ offs3) {
  __shared__ unsigned s[256];
  const int g = blockIdx.y;
  const int i = blockIdx.x * 256 + threadIdx.x;
  const unsigned v = (i < NNODES) ? deg3[(long)g * NNODES + i] : 0u;
  s[threadIdx.x] = v;
  __syncthreads();
#pragma unroll
  for (int o = 1; o < 256; o <<= 1) {
    unsigned t = (threadIdx.x >= o) ? s[threadIdx.x - o] : 0u;
    __syncthreads();
    s[threadIdx.x] += t;
    __syncthreads();
  }
  const unsigned excl = s[threadIdx.x] - v + boffs3[g * NB + blockIdx.x];
  if (i < NNODES) offs3[(long)g * OFFS_U32 + i] = excl;
}

__global__ __launch_bounds__(256) void scat3_k(const int* __restrict__ edges,
                                               const unsigned* __restrict__ offs3,
                                               const unsigned short* __restrict__ rank3,
                                               int* __restrict__ ssrc3) {
  const int g = blockIdx.y;
  const int e = blockIdx.x * 256 + threadIdx.x;
  if (e < NEDGES) {
    const int s = edges[(long)g * 2 * NEDGES + e];
    const int d = edges[(long)g * 2 * NEDGES + NEDGES + e];
    const unsigned p = offs3[(long)g * OFFS_U32 + d] + rank3[(long)g * NEDGES + e];
    ssrc3[(long)g * NEDGES + p] = s;
  }
}

__global__ __launch_bounds__(256) void zero_k(float4* __restrict__ p, long n4) {
  const long i = (long)blockIdx.x * 256 + threadIdx.x;
  if (i < n4) p[i] = (float4){0.f, 0.f, 0.f, 0.f};
}

extern "C" void kernel_launch(void* const* d_in, const int* in_sizes, int n_in,
                              void* d_out, int out_size, void* d_ws, size_t ws_size,
                              hipStream_t stream) {
  const float* feat = (const float*)d_in[0];
  const int* edges = (const int*)d_in[1];
  const float* Wp1 = (const float*)d_in[2];
  const float* bp1 = (const float*)d_in[3];
  const float* Ws1 = (const float*)d_in[4];
  const float* Wn1 = (const float*)d_in[5];
  const float* b1 = (const float*)d_in[6];
  const float* gamma = (const float*)d_in[7];
  const float* beta = (const float*)d_in[8];
  const float* Wp2 = (const float*)d_in[9];
  const float* bp2 = (const float*)d_in[10];
  const float* Ws2 = (const float*)d_in[11];
  const float* Wn2 = (const float*)d_in[12];
  const float* b2 = (const float*)d_in[13];

  // workspace layout (bytes, 128B-aligned); total ~117.2 MB
  char* w = (char*)d_ws;
  __bf16* m1 = (__bf16*)w;                          // 25.6 MB
  __bf16* hs1b = (__bf16*)(w + 25600000);           // 25.6 MB
  __bf16* h1b = (__bf16*)(w + 51200000);            // 25.6 MB (pre-BN layer-1 h)
  __bf16* m2 = (__bf16*)(w + 76800000);             // 25.6 MB
  unsigned* deg3 = (unsigned*)(w + 102400000);      // 1.2 MB
  unsigned* offs3 = (unsigned*)(w + 103600128);     // 1.2 MB
  unsigned* bsum3 = (unsigned*)(w + 104800512);     // 4.7 KB
  unsigned* boffs3 = (unsigned*)(w + 104805376);    // 4.7 KB
  unsigned short* rank3 = (unsigned short*)(w + 104810240);  // 3.84 MB
  int* ssrc3 = (int*)(w + 108650240);               // 7.68 MB
  float* pblk = (float*)(w + 116330240);            // 800 KB
  float* scsh = (float*)(w + 117131136);            // 1 KB

  const dim3 blk(256);
  const int edgeGrid = (NEDGES + 255) / 256;             // 2500
  const int degZeroGrid = (3 * NNODES / 4 + 255) / 256;  // 293

  // batched edge bucketing (counting sort by dst) for all 3 graphs
  zero_k<<<degZeroGrid, blk, 0, stream>>>((float4*)deg3, 3L * NNODES / 4);
  hist_rank3_k<<<dim3(edgeGrid, 3), blk, 0, stream>>>(edges, deg3, rank3);
  blocksum3_k<<<dim3(NB, 3), blk, 0, stream>>>(deg3, bsum3);
  scanb3_k<<<dim3(1, 3), dim3(512), 0, stream>>>(bsum3, boffs3, offs3);
  offsets3_k<<<dim3(NB, 3), blk, 0, stream>>>(deg3, boffs3, offs3);
  scat3_k<<<dim3(edgeGrid, 3), blk, 0, stream>>>(edges, offs3, rank3, ssrc3);

  // graph-independent heads: m1 = relu(feat@Wp1^T+bp1), hs1 = feat@Ws1^T+b1
  gemm_k<0, 0, false, true, true, false, false><<<GEMM_GRID, blk, 0, stream>>>(
      feat, nullptr, Wp1, nullptr, bp1, nullptr, nullptr, nullptr, nullptr, m1, nullptr, NNODES);
  gemm_k<0, 0, false, false, true, false, false><<<GEMM_GRID, blk, 0, stream>>>(
      feat, nullptr, Ws1, nullptr, b1, nullptr, nullptr, nullptr, nullptr, hs1b, nullptr, NNODES);

  for (int g = 0; g < 3; ++g) {
    const unsigned* offs = offs3 + (long)g * OFFS_U32;
    const int* ssrc = ssrc3 + (long)g * NEDGES;
    float* outg = (float*)d_out + (long)g * NNODES * FD;

    // layer 1: h1 = hs1 + segmax(m1)@Wn1^T (gather fused into A-load),
    // bf16 out + fused BN stats
    gemm_k<4, 0, false, false, true, true, true><<<GEMM_GRID, blk, 0, stream>>>(
        m1, nullptr, Wn1, nullptr, nullptr, hs1b, nullptr, ssrc, offs, h1b, pblk, NNODES);
    bn_final2_k<<<1, blk, 0, stream>>>(pblk, gamma, beta, scsh);

    // m2 = relu(bnrelu(h1)@Wp2^T + bp2)  (BN+relu fused into bf16 A-load)
    gemm_k<3, 0, false, true, true, false, false><<<GEMM_GRID, blk, 0, stream>>>(
        h1b, nullptr, Wp2, nullptr, bp2, nullptr, scsh, nullptr, nullptr, m2, nullptr, NNODES);

    // out = bnrelu(h1)@Ws2^T + segmax(m2)@Wn2^T + b2  -> d_out (f32)
    gemm_k<3, 4, true, false, false, false, false><<<GEMM_GRID, blk, 0, stream>>>(
        h1b, m2, Ws2, Wn2, b2, nullptr, scsh, ssrc, offs, outg, nullptr, NNODES);
  }
}

// Round 5
// 736.953 us; speedup vs baseline: 6.8906x; 1.3975x over previous
//
#include <hip/hip_runtime.h>
#include <hip/hip_bf16.h>

#define NNODES 100000
#define FD 128
#define NEDGES 640000
#define NB 391            // ceil(NNODES/256)
#define GEMM_GRID 782     // ceil(NNODES/128)
#define OFFS_U32 100032   // padded NNODES+1

typedef __bf16 bf16x8 __attribute__((ext_vector_type(8)));
typedef float f32x4 __attribute__((ext_vector_type(4)));
typedef unsigned short u16x8 __attribute__((ext_vector_type(8)));

__device__ __forceinline__ bf16x8 cvt8(float4 a, float4 b) {
  bf16x8 r;
  r[0] = (__bf16)a.x; r[1] = (__bf16)a.y; r[2] = (__bf16)a.z; r[3] = (__bf16)a.w;
  r[4] = (__bf16)b.x; r[5] = (__bf16)b.y; r[6] = (__bf16)b.z; r[7] = (__bf16)b.w;
  return r;
}

// ---- weight pre-pack: f32 [128][128] -> bf16 MFMA B-fragments ----
// frag f = (c*4+kk)*64 + lane; elem j = W[(c*16+(lane&15))][kk*32+(lane>>4)*8+j]
__global__ __launch_bounds__(256) void packw_k(const float* __restrict__ W,
                                               __bf16* __restrict__ out) {
  const int f = blockIdx.x * 256 + threadIdx.x;  // 2048 frags
  const int c = f >> 8, kk = (f >> 6) & 3, lane = f & 63;
  const int lr = lane & 15, lg = lane >> 4;
  const float* p = W + (c * 16 + lr) * FD + kk * 32 + lg * 8;
  *(bf16x8*)(out + (long)f * 8) = cvt8(*(const float4*)p, *(const float4*)(p + 4));
}

// A-row fragment loader: 4 x bf16x8 covering cols {kbase + kk*32 .. +8}.
// AM: 0 = f32, 1 = bf16, 3 = bf16 + fused BN+relu (scsh[0:128]=sc,[128:256]=sh)
template <int AM>
__device__ __forceinline__ void load_arow(const void* __restrict__ A, long row,
                                          int kbase, const float* __restrict__ scsh,
                                          bf16x8 (&af)[4]) {
  if constexpr (AM == 1) {
#pragma unroll
    for (int kk = 0; kk < 4; ++kk)
      af[kk] = *(const bf16x8*)((const __bf16*)A + row * FD + kbase + kk * 32);
  } else if constexpr (AM == 3) {
#pragma unroll
    for (int kk = 0; kk < 4; ++kk) {
      const int k = kbase + kk * 32;
      const bf16x8 r = *(const bf16x8*)((const __bf16*)A + row * FD + k);
      const float4 scx = *(const float4*)(scsh + k);
      const float4 scy = *(const float4*)(scsh + k + 4);
      const float4 shx = *(const float4*)(scsh + 128 + k);
      const float4 shy = *(const float4*)(scsh + 128 + k + 4);
      bf16x8 o;
      o[0] = (__bf16)fmaxf((float)r[0] * scx.x + shx.x, 0.f);
      o[1] = (__bf16)fmaxf((float)r[1] * scx.y + shx.y, 0.f);
      o[2] = (__bf16)fmaxf((float)r[2] * scx.z + shx.z, 0.f);
      o[3] = (__bf16)fmaxf((float)r[3] * scx.w + shx.w, 0.f);
      o[4] = (__bf16)fmaxf((float)r[4] * scy.x + shy.x, 0.f);
      o[5] = (__bf16)fmaxf((float)r[5] * scy.y + shy.y, 0.f);
      o[6] = (__bf16)fmaxf((float)r[6] * scy.z + shy.z, 0.f);
      o[7] = (__bf16)fmaxf((float)r[7] * scy.w + shy.w, 0.f);
      af[kk] = o;
    }
  } else {  // f32
#pragma unroll
    for (int kk = 0; kk < 4; ++kk) {
      const int k = kbase + kk * 32;
      const float* ap = (const float*)A + row * FD + k;
      af[kk] = cvt8(*(const float4*)ap, *(const float4*)(ap + 4));
    }
  }
}

// out[M x 128] = f(A0) @ W0^T (+ f(A1) @ W1^T) + bias, opt relu.
// W0p/W1p are pre-packed bf16 fragments. Wave: 32 rows x 128 cols.
// STATS: per-block column sum/sumsq of output -> pblk.
template <int A0M, int A1M, bool TWOA, bool RELU, bool OUTBF16, bool STATS>
__global__ __launch_bounds__(256, 3) void gemm_k(
    const void* __restrict__ A0, const void* __restrict__ A1,
    const __bf16* __restrict__ W0p, const __bf16* __restrict__ W1p,
    const float* __restrict__ bias, const float* __restrict__ scsh,
    void* __restrict__ outp, float* __restrict__ pblk, int M) {
  const int wid = threadIdx.x >> 6;
  const int lane = threadIdx.x & 63;
  const int lr = lane & 15;
  const int lg = lane >> 4;
  const int kbase = lg * 8;
  const int rbase = blockIdx.x * 128 + wid * 32;
  __shared__ float s_red[2][4][128];

  if constexpr (!STATS) {
    if (rbase >= M) return;  // wave-uniform; no barriers in this path
  }

  f32x4 acc[2][8];
#pragma unroll
  for (int t = 0; t < 2; ++t)
#pragma unroll
    for (int c = 0; c < 8; ++c) acc[t][c] = (f32x4){0.f, 0.f, 0.f, 0.f};

  // pass 0: all A-frags hoisted, then stream packed W per 16-col block
  {
    bf16x8 a0[2][4];
#pragma unroll
    for (int t = 0; t < 2; ++t) {
      long row = rbase + t * 16 + lr;
      if (row > M - 1) row = M - 1;  // clamp; stores guarded in epilogue
      load_arow<A0M>(A0, row, kbase, scsh, a0[t]);
    }
#pragma unroll
    for (int c = 0; c < 8; ++c) {
      bf16x8 bw[4];
#pragma unroll
      for (int kk = 0; kk < 4; ++kk)
        bw[kk] = *(const bf16x8*)(W0p + ((long)((c * 4 + kk) * 64 + lane)) * 8);
#pragma unroll
      for (int t = 0; t < 2; ++t)
#pragma unroll
        for (int kk = 0; kk < 4; ++kk)
          acc[t][c] = __builtin_amdgcn_mfma_f32_16x16x32_bf16(a0[t][kk], bw[kk], acc[t][c], 0, 0, 0);
    }
  }
  if constexpr (TWOA) {
    bf16x8 a1[2][4];
#pragma unroll
    for (int t = 0; t < 2; ++t) {
      long row = rbase + t * 16 + lr;
      if (row > M - 1) row = M - 1;
      load_arow<A1M>(A1, row, kbase, scsh, a1[t]);
    }
#pragma unroll
    for (int c = 0; c < 8; ++c) {
      bf16x8 bw[4];
#pragma unroll
      for (int kk = 0; kk < 4; ++kk)
        bw[kk] = *(const bf16x8*)(W1p + ((long)((c * 4 + kk) * 64 + lane)) * 8);
#pragma unroll
      for (int t = 0; t < 2; ++t)
#pragma unroll
        for (int kk = 0; kk < 4; ++kk)
          acc[t][c] = __builtin_amdgcn_mfma_f32_16x16x32_bf16(a1[t][kk], bw[kk], acc[t][c], 0, 0, 0);
    }
  }

  // epilogue: D(row = rbase + t*16 + lg*4 + j, col = c*16 + lr)
  float ps[8], pss[8];
#pragma unroll
  for (int c = 0; c < 8; ++c) { ps[c] = 0.f; pss[c] = 0.f; }

#pragma unroll
  for (int t = 0; t < 2; ++t)
#pragma unroll
    for (int j = 0; j < 4; ++j) {
      const int row = rbase + t * 16 + lg * 4 + j;
      if (row < M) {
#pragma unroll
        for (int c = 0; c < 8; ++c) {
          const int col = c * 16 + lr;
          float v = acc[t][c][j];
          if (bias) v += bias[col];
          if constexpr (STATS) { ps[c] += v; pss[c] += v * v; }
          if constexpr (RELU) v = fmaxf(v, 0.f);
          if constexpr (OUTBF16)
            ((__bf16*)outp)[(long)row * FD + col] = (__bf16)v;
          else
            ((float*)outp)[(long)row * FD + col] = v;
        }
      }
    }

  if constexpr (STATS) {
#pragma unroll
    for (int c = 0; c < 8; ++c) {
      float s = ps[c], ss = pss[c];
      s += __shfl_xor(s, 16); s += __shfl_xor(s, 32);
      ss += __shfl_xor(ss, 16); ss += __shfl_xor(ss, 32);
      if (lane < 16) {
        s_red[0][wid][c * 16 + lr] = s;
        s_red[1][wid][c * 16 + lr] = ss;
      }
    }
    __syncthreads();
    const int tid = threadIdx.x;
    const int which = tid >> 7, col = tid & 127;
    pblk[(long)blockIdx.x * 256 + tid] =
        s_red[which][0][col] + s_red[which][1][col] + s_red[which][2][col] + s_red[which][3][col];
  }
}

// ---- BN partial reductions -> scale/shift ----
__global__ __launch_bounds__(256) void bn_red1_k(const float* __restrict__ pblk,
                                                 float* __restrict__ pblk2) {
  const int tid = threadIdx.x;
  float s = 0.f;
  for (int r = blockIdx.x; r < GEMM_GRID; r += 64) s += pblk[(long)r * 256 + tid];
  pblk2[blockIdx.x * 256 + tid] = s;
}

__global__ __launch_bounds__(256) void bn_final2_k(const float* __restrict__ pblk2,
                                                   const float* __restrict__ gamma,
                                                   const float* __restrict__ beta,
                                                   float* __restrict__ scsh) {
  __shared__ float s_ss[128];
  const int tid = threadIdx.x;
  float s = 0.f;
#pragma unroll
  for (int r = 0; r < 64; ++r) s += pblk2[r * 256 + tid];
  if (tid >= 128) s_ss[tid - 128] = s;
  __syncthreads();
  if (tid < 128) {
    const float mu = s / (float)NNODES;
    const float var = s_ss[tid] / (float)NNODES - mu * mu;
    const float sc = rsqrtf(var + 1e-5f) * gamma[tid];
    scsh[tid] = sc;
    scsh[128 + tid] = beta[tid] - mu * sc;
  }
}

// ---- batched (3-graph) counting-sort, rank-trick (atomics only in hist) ----

__global__ __launch_bounds__(256) void hist_rank3_k(const int* __restrict__ edges,
                                                    unsigned* __restrict__ deg3,
                                                    unsigned short* __restrict__ rank3) {
  const int g = blockIdx.y;
  const int e = blockIdx.x * 256 + threadIdx.x;
  if (e < NEDGES) {
    const int d = edges[(long)g * 2 * NEDGES + NEDGES + e];
    const unsigned r = atomicAdd(&deg3[(long)g * NNODES + d], 1u);
    rank3[(long)g * NEDGES + e] = (unsigned short)r;
  }
}

__global__ __launch_bounds__(256) void blocksum3_k(const unsigned* __restrict__ deg3,
                                                   unsigned* __restrict__ bsum3) {
  __shared__ unsigned s[256];
  const int g = blockIdx.y;
  const int i = blockIdx.x * 256 + threadIdx.x;
  s[threadIdx.x] = (i < NNODES) ? deg3[(long)g * NNODES + i] : 0u;
  __syncthreads();
#pragma unroll
  for (int o = 128; o > 0; o >>= 1) {
    if (threadIdx.x < o) s[threadIdx.x] += s[threadIdx.x + o];
    __syncthreads();
  }
  if (threadIdx.x == 0) bsum3[g * NB + blockIdx.x] = s[0];
}

__global__ __launch_bounds__(512) void scanb3_k(const unsigned* __restrict__ bsum3,
                                                unsigned* __restrict__ boffs3,
                                                unsigned* __restrict__ offs3) {
  __shared__ unsigned s[512];
  const int g = blockIdx.y;
  const unsigned v = (threadIdx.x < NB) ? bsum3[g * NB + threadIdx.x] : 0u;
  s[threadIdx.x] = v;
  __syncthreads();
#pragma unroll
  for (int o = 1; o < 512; o <<= 1) {
    unsigned t = (threadIdx.x >= o) ? s[threadIdx.x - o] : 0u;
    __syncthreads();
    s[threadIdx.x] += t;
    __syncthreads();
  }
  if (threadIdx.x < NB) boffs3[g * NB + threadIdx.x] = s[threadIdx.x] - v;
  if (threadIdx.x == 0) offs3[(long)g * OFFS_U32 + NNODES] = NEDGES;
}

__global__ __launch_bounds__(256) void offsets3_k(const unsigned* __restrict__ deg3,
                                                  const unsigned* __restrict__ boffs3,
                                                  unsigned* __restrict__ offs3) {
  __shared__ unsigned s[256];
  const int g = blockIdx.y;
  const int i = blockIdx.x * 256 + threadIdx.x;
  const unsigned v = (i < NNODES) ? deg3[(long)g * NNODES + i] : 0u;
  s[threadIdx.x] = v;
  __syncthreads();
#pragma unroll
  for (int o = 1; o < 256; o <<= 1) {
    unsigned t = (threadIdx.x >= o) ? s[threadIdx.x - o] : 0u;
    __syncthreads();
    s[threadIdx.x] += t;
    __syncthreads();
  }
  const unsigned excl = s[threadIdx.x] - v + boffs3[g * NB + blockIdx.x];
  if (i < NNODES) offs3[(long)g * OFFS_U32 + i] = excl;
}

__global__ __launch_bounds__(256) void scat3_k(const int* __restrict__ edges,
                                               const unsigned* __restrict__ offs3,
                                               const unsigned short* __restrict__ rank3,
                                               int* __restrict__ ssrc3) {
  const int g = blockIdx.y;
  const int e = blockIdx.x * 256 + threadIdx.x;
  if (e < NEDGES) {
    const int s = edges[(long)g * 2 * NEDGES + e];
    const int d = edges[(long)g * 2 * NEDGES + NEDGES + e];
    const unsigned p = offs3[(long)g * OFFS_U32 + d] + rank3[(long)g * NEDGES + e];
    ssrc3[(long)g * NEDGES + p] = s;
  }
}

// 16 lanes per node; max over in-edges (bf16 >= 0 -> u16 bit-compare exact).
// Each edge iteration reads a full contiguous 256B source row per node-group.
__global__ __launch_bounds__(256) void agg_k(const unsigned short* __restrict__ m,
                                             const int* __restrict__ ssrc,
                                             const unsigned* __restrict__ offs,
                                             unsigned short* __restrict__ agg) {
  const int gid = blockIdx.x * 256 + threadIdx.x;
  const int node = gid >> 4;
  if (node >= NNODES) return;
  const int fl = (gid & 15) * 8;
  const unsigned beg = offs[node], end = offs[node + 1];
  u16x8 acc = {0, 0, 0, 0, 0, 0, 0, 0};
  unsigned i = beg;
  for (; i + 2 <= end; i += 2) {
    const int s0 = ssrc[i];
    const int s1 = ssrc[i + 1];
    const u16x8 v0 = *(const u16x8*)(m + (long)s0 * FD + fl);
    const u16x8 v1 = *(const u16x8*)(m + (long)s1 * FD + fl);
#pragma unroll
    for (int j = 0; j < 8; ++j) {
      const unsigned short mx = v0[j] > v1[j] ? v0[j] : v1[j];
      acc[j] = mx > acc[j] ? mx : acc[j];
    }
  }
  if (i < end) {
    const u16x8 v = *(const u16x8*)(m + (long)ssrc[i] * FD + fl);
#pragma unroll
    for (int j = 0; j < 8; ++j) acc[j] = v[j] > acc[j] ? v[j] : acc[j];
  }
  *(u16x8*)(agg + (long)node * FD + fl) = acc;
}

__global__ __launch_bounds__(256) void zero_k(float4* __restrict__ p, long n4) {
  const long i = (long)blockIdx.x * 256 + threadIdx.x;
  if (i < n4) p[i] = (float4){0.f, 0.f, 0.f, 0.f};
}

extern "C" void kernel_launch(void* const* d_in, const int* in_sizes, int n_in,
                              void* d_out, int out_size, void* d_ws, size_t ws_size,
                              hipStream_t stream) {
  const float* feat = (const float*)d_in[0];
  const int* edges = (const int*)d_in[1];
  const float* Wp1 = (const float*)d_in[2];
  const float* bp1 = (const float*)d_in[3];
  const float* Ws1 = (const float*)d_in[4];
  const float* Wn1 = (const float*)d_in[5];
  const float* b1 = (const float*)d_in[6];
  const float* gamma = (const float*)d_in[7];
  const float* beta = (const float*)d_in[8];
  const float* Wp2 = (const float*)d_in[9];
  const float* bp2 = (const float*)d_in[10];
  const float* Ws2 = (const float*)d_in[11];
  const float* Wn2 = (const float*)d_in[12];
  const float* b2 = (const float*)d_in[13];

  // workspace layout (bytes, 128B-aligned)
  char* w = (char*)d_ws;
  __bf16* m1 = (__bf16*)w;                          // 25.6 MB
  __bf16* h1b = (__bf16*)(w + 25600000);            // 25.6 MB (pre-BN layer-1 h)
  __bf16* aggb = (__bf16*)(w + 51200000);           // 25.6 MB
  __bf16* m2 = (__bf16*)(w + 76800000);             // 25.6 MB
  __bf16* wpk = (__bf16*)(w + 102400000);           // 6 x 32 KB packed weights
  unsigned* deg3 = (unsigned*)(w + 102600192);      // 1.2 MB
  unsigned* offs3 = (unsigned*)(w + 103800320);     // 1.2 MB
  unsigned* bsum3 = (unsigned*)(w + 105000704);     // 4.7 KB
  unsigned* boffs3 = (unsigned*)(w + 105005568);    // 4.7 KB
  unsigned short* rank3 = (unsigned short*)(w + 105010432);  // 3.84 MB
  int* ssrc3 = (int*)(w + 108850432);               // 7.68 MB
  float* pblk = (float*)(w + 116530432);            // 800 KB
  float* pblk2 = (float*)(w + 117331456);           // 64 KB
  float* scsh = (float*)(w + 117396992);            // 1 KB

  __bf16* Wp1p = wpk;
  __bf16* Ws1p = wpk + 16384;
  __bf16* Wn1p = wpk + 2 * 16384;
  __bf16* Wp2p = wpk + 3 * 16384;
  __bf16* Ws2p = wpk + 4 * 16384;
  __bf16* Wn2p = wpk + 5 * 16384;

  const dim3 blk(256);
  const int edgeGrid = (NEDGES + 255) / 256;             // 2500
  const int aggGrid = (NNODES * 16 + 255) / 256;         // 6250
  const int degZeroGrid = (3 * NNODES / 4 + 255) / 256;  // 293

  // pack weights (tiny)
  packw_k<<<8, blk, 0, stream>>>(Wp1, Wp1p);
  packw_k<<<8, blk, 0, stream>>>(Ws1, Ws1p);
  packw_k<<<8, blk, 0, stream>>>(Wn1, Wn1p);
  packw_k<<<8, blk, 0, stream>>>(Wp2, Wp2p);
  packw_k<<<8, blk, 0, stream>>>(Ws2, Ws2p);
  packw_k<<<8, blk, 0, stream>>>(Wn2, Wn2p);

  // batched edge bucketing (counting sort by dst) for all 3 graphs
  zero_k<<<degZeroGrid, blk, 0, stream>>>((float4*)deg3, 3L * NNODES / 4);
  hist_rank3_k<<<dim3(edgeGrid, 3), blk, 0, stream>>>(edges, deg3, rank3);
  blocksum3_k<<<dim3(NB, 3), blk, 0, stream>>>(deg3, bsum3);
  scanb3_k<<<dim3(1, 3), dim3(512), 0, stream>>>(bsum3, boffs3, offs3);
  offsets3_k<<<dim3(NB, 3), blk, 0, stream>>>(deg3, boffs3, offs3);
  scat3_k<<<dim3(edgeGrid, 3), blk, 0, stream>>>(edges, offs3, rank3, ssrc3);

  // graph-independent head: m1 = relu(feat@Wp1^T + bp1)
  gemm_k<0, 0, false, true, true, false><<<GEMM_GRID, blk, 0, stream>>>(
      feat, nullptr, Wp1p, nullptr, bp1, nullptr, m1, nullptr, NNODES);

  for (int g = 0; g < 3; ++g) {
    const unsigned* offs = offs3 + (long)g * OFFS_U32;
    const int* ssrc = ssrc3 + (long)g * NEDGES;
    float* outg = (float*)d_out + (long)g * NNODES * FD;

    // layer 1: h1 = segmax(m1)@Wn1^T + feat@Ws1^T + b1 (bf16) + fused BN stats
    agg_k<<<aggGrid, blk, 0, stream>>>((const unsigned short*)m1, ssrc, offs,
                                       (unsigned short*)aggb);
    gemm_k<1, 0, true, false, true, true><<<GEMM_GRID, blk, 0, stream>>>(
        aggb, feat, Wn1p, Ws1p, b1, nullptr, h1b, pblk, NNODES);
    bn_red1_k<<<64, blk, 0, stream>>>(pblk, pblk2);
    bn_final2_k<<<1, blk, 0, stream>>>(pblk2, gamma, beta, scsh);

    // m2 = relu(bnrelu(h1)@Wp2^T + bp2)  (BN+relu fused into bf16 A-load)
    gemm_k<3, 0, false, true, true, false><<<GEMM_GRID, blk, 0, stream>>>(
        h1b, nullptr, Wp2p, nullptr, bp2, scsh, m2, nullptr, NNODES);

    // out = bnrelu(h1)@Ws2^T + segmax(m2)@Wn2^T + b2  -> d_out (f32)
    agg_k<<<aggGrid, blk, 0, stream>>>((const unsigned short*)m2, ssrc, offs,
                                       (unsigned short*)aggb);
    gemm_k<3, 1, true, false, false, false><<<GEMM_GRID, blk, 0, stream>>>(
        h1b, aggb, Ws2p, Wn2p, b2, scsh, outg, nullptr, NNODES);
  }
}

// Round 6
// 582.798 us; speedup vs baseline: 8.7133x; 1.2645x over previous
//
#include <hip/hip_runtime.h>
#include <hip/hip_bf16.h>

#define NNODES 100000
#define FD 128
#define NEDGES 640000
#define NB 391            // ceil(NNODES/256)
#define GEMM_GRID 782     // ceil(NNODES/128)
#define OFFS_U32 100032   // padded NNODES+1

typedef __bf16 bf16x8 __attribute__((ext_vector_type(8)));
typedef __bf16 bf16x4 __attribute__((ext_vector_type(4)));
typedef float f32x4 __attribute__((ext_vector_type(4)));
typedef unsigned short u16x8 __attribute__((ext_vector_type(8)));

__device__ __forceinline__ bf16x8 cvt8(float4 a, float4 b) {
  bf16x8 r;
  r[0] = (__bf16)a.x; r[1] = (__bf16)a.y; r[2] = (__bf16)a.z; r[3] = (__bf16)a.w;
  r[4] = (__bf16)b.x; r[5] = (__bf16)b.y; r[6] = (__bf16)b.z; r[7] = (__bf16)b.w;
  return r;
}

// ---- pack all 6 weight matrices f32[128][128] -> bf16 MFMA fragments ----
// frag f = (c*4+kk)*64 + lane; elem j = W[(c*16+(lane&15))][kk*32+(lane>>4)*8+j]
__global__ __launch_bounds__(256) void packw6_k(
    const float* __restrict__ W0, const float* __restrict__ W1,
    const float* __restrict__ W2, const float* __restrict__ W3,
    const float* __restrict__ W4, const float* __restrict__ W5,
    __bf16* __restrict__ out) {
  const int gidx = blockIdx.x * 256 + threadIdx.x;  // 0..12287
  const int wi = gidx >> 11;
  const int f = gidx & 2047;
  const float* W = wi == 0 ? W0 : wi == 1 ? W1 : wi == 2 ? W2
                 : wi == 3 ? W3 : wi == 4 ? W4 : W5;
  const int c = f >> 8, kk = (f >> 6) & 3, lane = f & 63;
  const int lr = lane & 15, lg = lane >> 4;
  const float* p = W + (c * 16 + lr) * FD + kk * 32 + lg * 8;
  *(bf16x8*)(out + (long)gidx * 8) = cvt8(*(const float4*)p, *(const float4*)(p + 4));
}

// A-row fragment loader: 4 x bf16x8 covering cols {kbase + kk*32 .. +8}.
// AM: 0 = f32, 1 = bf16, 3 = bf16 + fused BN+relu (scsh[0:128]=sc,[128:256]=sh)
template <int AM>
__device__ __forceinline__ void load_arow(const void* __restrict__ A, long row,
                                          int kbase, const float* __restrict__ scsh,
                                          bf16x8 (&af)[4]) {
  if constexpr (AM == 1) {
#pragma unroll
    for (int kk = 0; kk < 4; ++kk)
      af[kk] = *(const bf16x8*)((const __bf16*)A + row * FD + kbase + kk * 32);
  } else if constexpr (AM == 3) {
#pragma unroll
    for (int kk = 0; kk < 4; ++kk) {
      const int k = kbase + kk * 32;
      const bf16x8 r = *(const bf16x8*)((const __bf16*)A + row * FD + k);
      const float4 scx = *(const float4*)(scsh + k);
      const float4 scy = *(const float4*)(scsh + k + 4);
      const float4 shx = *(const float4*)(scsh + 128 + k);
      const float4 shy = *(const float4*)(scsh + 128 + k + 4);
      bf16x8 o;
      o[0] = (__bf16)fmaxf((float)r[0] * scx.x + shx.x, 0.f);
      o[1] = (__bf16)fmaxf((float)r[1] * scx.y + shx.y, 0.f);
      o[2] = (__bf16)fmaxf((float)r[2] * scx.z + shx.z, 0.f);
      o[3] = (__bf16)fmaxf((float)r[3] * scx.w + shx.w, 0.f);
      o[4] = (__bf16)fmaxf((float)r[4] * scy.x + shy.x, 0.f);
      o[5] = (__bf16)fmaxf((float)r[5] * scy.y + shy.y, 0.f);
      o[6] = (__bf16)fmaxf((float)r[6] * scy.z + shy.z, 0.f);
      o[7] = (__bf16)fmaxf((float)r[7] * scy.w + shy.w, 0.f);
      af[kk] = o;
    }
  } else {  // f32
#pragma unroll
    for (int kk = 0; kk < 4; ++kk) {
      const int k = kbase + kk * 32;
      const float* ap = (const float*)A + row * FD + k;
      af[kk] = cvt8(*(const float4*)ap, *(const float4*)(ap + 4));
    }
  }
}

// out[g][M x 128] = f(A0[g]) @ W0^T (+ f(A1[g]) @ W1^T) + bias, opt relu.
// Swapped-operand MFMA: D[row=rbase+t*16+lr][col=c*16+lg*4+j] = acc[t][c][j]
// -> vectorized 16B (f32) / 8B (bf16) epilogue stores, float4 bias.
// WRITEB: also emit bf16 copy of A0 (head GEMM -> featb).
// STATS: per-block column sum/sumsq -> pblk (batched per g).
// Strides a0s/a1s/os in BYTES; grid (GEMM_GRID, ngraphs).
template <int A0M, int A1M, bool TWOA, bool RELU, bool OUTBF16, bool STATS, bool WRITEB>
__global__ __launch_bounds__(256, 3) void gemm_k(
    const void* __restrict__ A0, long a0s, const void* __restrict__ A1, long a1s,
    const __bf16* __restrict__ W0p, const __bf16* __restrict__ W1p,
    const float* __restrict__ bias, const float* __restrict__ scsh0,
    void* __restrict__ outp, long os, float* __restrict__ pblk,
    __bf16* __restrict__ bcopy, int M) {
  const int g = blockIdx.y;
  const int wid = threadIdx.x >> 6;
  const int lane = threadIdx.x & 63;
  const int lr = lane & 15;
  const int lg = lane >> 4;
  const int kbase = lg * 8;
  const int rbase = blockIdx.x * 128 + wid * 32;
  __shared__ float s_red[2][4][128];

  const void* A0g = (const char*)A0 + (long)g * a0s;
  const void* A1g = (const char*)A1 + (TWOA ? (long)g * a1s : 0);
  void* outg = (char*)outp + (long)g * os;
  const float* scshg = (A0M == 3 || A1M == 3) ? scsh0 + (long)g * 256 : nullptr;
  float* pblkg = STATS ? pblk + (long)g * ((long)GEMM_GRID * 256) : nullptr;

  if constexpr (!STATS) {
    if (rbase >= M) return;  // wave-uniform; no barriers in this path
  }

  f32x4 acc[2][8];
#pragma unroll
  for (int t = 0; t < 2; ++t)
#pragma unroll
    for (int c = 0; c < 8; ++c) acc[t][c] = (f32x4){0.f, 0.f, 0.f, 0.f};

  {
    bf16x8 a0[2][4];
#pragma unroll
    for (int t = 0; t < 2; ++t) {
      long row = rbase + t * 16 + lr;
      if (row > M - 1) row = M - 1;  // clamp; stores guarded in epilogue
      load_arow<A0M>(A0g, row, kbase, scshg, a0[t]);
    }
    if constexpr (WRITEB) {
#pragma unroll
      for (int t = 0; t < 2; ++t) {
        const int row = rbase + t * 16 + lr;
        if (row < M)
#pragma unroll
          for (int kk = 0; kk < 4; ++kk)
            *(bf16x8*)(bcopy + (long)row * FD + kbase + kk * 32) = a0[t][kk];
      }
    }
#pragma unroll
    for (int c = 0; c < 8; ++c) {
      bf16x8 bw[4];
#pragma unroll
      for (int kk = 0; kk < 4; ++kk)
        bw[kk] = *(const bf16x8*)(W0p + ((long)((c * 4 + kk) * 64 + lane)) * 8);
#pragma unroll
      for (int t = 0; t < 2; ++t)
#pragma unroll
        for (int kk = 0; kk < 4; ++kk)
          acc[t][c] = __builtin_amdgcn_mfma_f32_16x16x32_bf16(bw[kk], a0[t][kk], acc[t][c], 0, 0, 0);
    }
  }
  if constexpr (TWOA) {
    bf16x8 a1[2][4];
#pragma unroll
    for (int t = 0; t < 2; ++t) {
      long row = rbase + t * 16 + lr;
      if (row > M - 1) row = M - 1;
      load_arow<A1M>(A1g, row, kbase, scshg, a1[t]);
    }
#pragma unroll
    for (int c = 0; c < 8; ++c) {
      bf16x8 bw[4];
#pragma unroll
      for (int kk = 0; kk < 4; ++kk)
        bw[kk] = *(const bf16x8*)(W1p + ((long)((c * 4 + kk) * 64 + lane)) * 8);
#pragma unroll
      for (int t = 0; t < 2; ++t)
#pragma unroll
        for (int kk = 0; kk < 4; ++kk)
          acc[t][c] = __builtin_amdgcn_mfma_f32_16x16x32_bf16(bw[kk], a1[t][kk], acc[t][c], 0, 0, 0);
    }
  }

  // epilogue: lane holds D[row = rbase+t*16+lr][cols c*16+lg*4 .. +3]
  float ps[8][4], pss[8][4];
  if constexpr (STATS) {
#pragma unroll
    for (int c = 0; c < 8; ++c)
#pragma unroll
      for (int j = 0; j < 4; ++j) { ps[c][j] = 0.f; pss[c][j] = 0.f; }
  }

#pragma unroll
  for (int t = 0; t < 2; ++t) {
    const int row = rbase + t * 16 + lr;
    const bool ok = row < M;
#pragma unroll
    for (int c = 0; c < 8; ++c) {
      const int cb = c * 16 + lg * 4;
      f32x4 v = acc[t][c];
      if (bias) {
        const float4 bv = *(const float4*)(bias + cb);
        v[0] += bv.x; v[1] += bv.y; v[2] += bv.z; v[3] += bv.w;
      }
      if constexpr (STATS) {
        if (ok) {
#pragma unroll
          for (int j = 0; j < 4; ++j) { ps[c][j] += v[j]; pss[c][j] += v[j] * v[j]; }
        }
      }
      if constexpr (RELU) {
#pragma unroll
        for (int j = 0; j < 4; ++j) v[j] = fmaxf(v[j], 0.f);
      }
      if (ok) {
        if constexpr (OUTBF16) {
          bf16x4 o;
          o[0] = (__bf16)v[0]; o[1] = (__bf16)v[1];
          o[2] = (__bf16)v[2]; o[3] = (__bf16)v[3];
          *(bf16x4*)((__bf16*)outg + (long)row * FD + cb) = o;
        } else {
          *(f32x4*)((float*)outg + (long)row * FD + cb) = v;
        }
      }
    }
  }

  if constexpr (STATS) {
    // reduce over the 16 lr-lanes (rows) within each lg group
#pragma unroll
    for (int c = 0; c < 8; ++c)
#pragma unroll
      for (int j = 0; j < 4; ++j) {
        float s = ps[c][j], q = pss[c][j];
        s += __shfl_xor(s, 1); s += __shfl_xor(s, 2);
        s += __shfl_xor(s, 4); s += __shfl_xor(s, 8);
        q += __shfl_xor(q, 1); q += __shfl_xor(q, 2);
        q += __shfl_xor(q, 4); q += __shfl_xor(q, 8);
        if (lr == 0) {
          s_red[0][wid][c * 16 + lg * 4 + j] = s;
          s_red[1][wid][c * 16 + lg * 4 + j] = q;
        }
      }
    __syncthreads();
    const int tid = threadIdx.x;
    const int which = tid >> 7, col = tid & 127;
    pblkg[(long)blockIdx.x * 256 + tid] =
        s_red[which][0][col] + s_red[which][1][col] + s_red[which][2][col] + s_red[which][3][col];
  }
}

// ---- BN partial reductions -> scale/shift (batched over g) ----
__global__ __launch_bounds__(256) void bn_red1_k(const float* __restrict__ pblk,
                                                 float* __restrict__ pblk2) {
  const int g = blockIdx.y;
  const float* p = pblk + (long)g * GEMM_GRID * 256;
  float s = 0.f;
  for (int r = blockIdx.x; r < GEMM_GRID; r += 64) s += p[(long)r * 256 + threadIdx.x];
  pblk2[((long)g * 64 + blockIdx.x) * 256 + threadIdx.x] = s;
}

__global__ __launch_bounds__(256) void bn_final2_k(const float* __restrict__ pblk2,
                                                   const float* __restrict__ gamma,
                                                   const float* __restrict__ beta,
                                                   float* __restrict__ scsh3) {
  __shared__ float s_ss[128];
  const int g = blockIdx.y;
  const int tid = threadIdx.x;
  const float* p = pblk2 + (long)g * 64 * 256;
  float s = 0.f;
#pragma unroll
  for (int r = 0; r < 64; ++r) s += p[r * 256 + tid];
  if (tid >= 128) s_ss[tid - 128] = s;
  __syncthreads();
  if (tid < 128) {
    const float mu = s / (float)NNODES;
    const float var = s_ss[tid] / (float)NNODES - mu * mu;
    const float sc = rsqrtf(var + 1e-5f) * gamma[tid];
    scsh3[g * 256 + tid] = sc;
    scsh3[g * 256 + 128 + tid] = beta[tid] - mu * sc;
  }
}

// ---- batched (3-graph) counting-sort, rank-trick (atomics only in hist) ----

__global__ __launch_bounds__(256) void hist_rank3_k(const int* __restrict__ edges,
                                                    unsigned* __restrict__ deg3,
                                                    unsigned short* __restrict__ rank3) {
  const int g = blockIdx.y;
  const int e = blockIdx.x * 256 + threadIdx.x;
  if (e < NEDGES) {
    const int d = edges[(long)g * 2 * NEDGES + NEDGES + e];
    const unsigned r = atomicAdd(&deg3[(long)g * NNODES + d], 1u);
    rank3[(long)g * NEDGES + e] = (unsigned short)r;
  }
}

__global__ __launch_bounds__(256) void blocksum3_k(const unsigned* __restrict__ deg3,
                                                   unsigned* __restrict__ bsum3) {
  __shared__ unsigned s[256];
  const int g = blockIdx.y;
  const int i = blockIdx.x * 256 + threadIdx.x;
  s[threadIdx.x] = (i < NNODES) ? deg3[(long)g * NNODES + i] : 0u;
  __syncthreads();
#pragma unroll
  for (int o = 128; o > 0; o >>= 1) {
    if (threadIdx.x < o) s[threadIdx.x] += s[threadIdx.x + o];
    __syncthreads();
  }
  if (threadIdx.x == 0) bsum3[g * NB + blockIdx.x] = s[0];
}

__global__ __launch_bounds__(512) void scanb3_k(const unsigned* __restrict__ bsum3,
                                                unsigned* __restrict__ boffs3,
                                                unsigned* __restrict__ offs3) {
  __shared__ unsigned s[512];
  const int g = blockIdx.y;
  const unsigned v = (threadIdx.x < NB) ? bsum3[g * NB + threadIdx.x] : 0u;
  s[threadIdx.x] = v;
  __syncthreads();
#pragma unroll
  for (int o = 1; o < 512; o <<= 1) {
    unsigned t = (threadIdx.x >= o) ? s[threadIdx.x - o] : 0u;
    __syncthreads();
    s[threadIdx.x] += t;
    __syncthreads();
  }
  if (threadIdx.x < NB) boffs3[g * NB + threadIdx.x] = s[threadIdx.x] - v;
  if (threadIdx.x == 0) offs3[(long)g * OFFS_U32 + NNODES] = NEDGES;
}

__global__ __launch_bounds__(256) void offsets3_k(const unsigned* __restrict__ deg3,
                                                  const unsigned* __restrict__ boffs3,
                                                  unsigned* __restrict__ offs3) {
  __shared__ unsigned s[256];
  const int g = blockIdx.y;
  const int i = blockIdx.x * 256 + threadIdx.x;
  const unsigned v = (i < NNODES) ? deg3[(long)g * NNODES + i] : 0u;
  s[threadIdx.x] = v;
  __syncthreads();
#pragma unroll
  for (int o = 1; o < 256; o <<= 1) {
    unsigned t = (threadIdx.x >= o) ? s[threadIdx.x - o] : 0u;
    __syncthreads();
    s[threadIdx.x] += t;
    __syncthreads();
  }
  const unsigned excl = s[threadIdx.x] - v + boffs3[g * NB + blockIdx.x];
  if (i < NNODES) offs3[(long)g * OFFS_U32 + i] = excl;
}

__global__ __launch_bounds__(256) void scat3_k(const int* __restrict__ edges,
                                               const unsigned* __restrict__ offs3,
                                               const unsigned short* __restrict__ rank3,
                                               int* __restrict__ ssrc3) {
  const int g = blockIdx.y;
  const int e = blockIdx.x * 256 + threadIdx.x;
  if (e < NEDGES) {
    const int s = edges[(long)g * 2 * NEDGES + e];
    const int d = edges[(long)g * 2 * NEDGES + NEDGES + e];
    const unsigned p = offs3[(long)g * OFFS_U32 + d] + rank3[(long)g * NEDGES + e];
    ssrc3[(long)g * NEDGES + p] = s;
  }
}

// 16 lanes per node; max over in-edges (bf16 >= 0 -> u16 bit-compare exact).
// Batched over g: m stride ms elements (0 = shared input).
__global__ __launch_bounds__(256) void agg_k(const unsigned short* __restrict__ m,
                                             long ms, const int* __restrict__ ssrc3,
                                             const unsigned* __restrict__ offs3,
                                             unsigned short* __restrict__ agg3) {
  const int g = blockIdx.y;
  const unsigned short* mg = m + (long)g * ms;
  const int* ssrc = ssrc3 + (long)g * NEDGES;
  const unsigned* offs = offs3 + (long)g * OFFS_U32;
  unsigned short* agg = agg3 + (long)g * NNODES * FD;

  const int gid = blockIdx.x * 256 + threadIdx.x;
  const int node = gid >> 4;
  if (node >= NNODES) return;
  const int fl = (gid & 15) * 8;
  const unsigned beg = offs[node], end = offs[node + 1];
  u16x8 acc = {0, 0, 0, 0, 0, 0, 0, 0};
  unsigned i = beg;
  for (; i + 2 <= end; i += 2) {
    const int s0 = ssrc[i];
    const int s1 = ssrc[i + 1];
    const u16x8 v0 = *(const u16x8*)(mg + (long)s0 * FD + fl);
    const u16x8 v1 = *(const u16x8*)(mg + (long)s1 * FD + fl);
#pragma unroll
    for (int j = 0; j < 8; ++j) {
      const unsigned short mx = v0[j] > v1[j] ? v0[j] : v1[j];
      acc[j] = mx > acc[j] ? mx : acc[j];
    }
  }
  if (i < end) {
    const u16x8 v = *(const u16x8*)(mg + (long)ssrc[i] * FD + fl);
#pragma unroll
    for (int j = 0; j < 8; ++j) acc[j] = v[j] > acc[j] ? v[j] : acc[j];
  }
  *(u16x8*)(agg + (long)node * FD + fl) = acc;
}

__global__ __launch_bounds__(256) void zero_k(float4* __restrict__ p, long n4) {
  const long i = (long)blockIdx.x * 256 + threadIdx.x;
  if (i < n4) p[i] = (float4){0.f, 0.f, 0.f, 0.f};
}

extern "C" void kernel_launch(void* const* d_in, const int* in_sizes, int n_in,
                              void* d_out, int out_size, void* d_ws, size_t ws_size,
                              hipStream_t stream) {
  const float* feat = (const float*)d_in[0];
  const int* edges = (const int*)d_in[1];
  const float* Wp1 = (const float*)d_in[2];
  const float* bp1 = (const float*)d_in[3];
  const float* Ws1 = (const float*)d_in[4];
  const float* Wn1 = (const float*)d_in[5];
  const float* b1 = (const float*)d_in[6];
  const float* gamma = (const float*)d_in[7];
  const float* beta = (const float*)d_in[8];
  const float* Wp2 = (const float*)d_in[9];
  const float* bp2 = (const float*)d_in[10];
  const float* Ws2 = (const float*)d_in[11];
  const float* Wn2 = (const float*)d_in[12];
  const float* b2 = (const float*)d_in[13];

  const long SZ_BF = 25600000;   // bf16 [N][128] bytes
  const long SZ_F32 = 51200000;  // f32  [N][128] bytes

  // workspace layout (bytes, 128B-aligned); total ~298.3 MB
  char* w = (char*)d_ws;
  __bf16* m1 = (__bf16*)w;                          // 25.6 MB
  __bf16* featb = (__bf16*)(w + 25600000);          // 25.6 MB
  __bf16* h1b3 = (__bf16*)(w + 51200000);           // 76.8 MB (3x pre-BN h1)
  __bf16* aggb3 = (__bf16*)(w + 128000000);         // 76.8 MB
  __bf16* m2_3 = (__bf16*)(w + 204800000);          // 76.8 MB
  __bf16* wpk = (__bf16*)(w + 281600000);           // 192 KB packed weights
  unsigned* deg3 = (unsigned*)(w + 281796608);      // 1.2 MB
  unsigned* offs3 = (unsigned*)(w + 282996608);     // 1.2 MB
  unsigned* bsum3 = (unsigned*)(w + 284196992);     // 4.7 KB
  unsigned* boffs3 = (unsigned*)(w + 284201728);    // 4.7 KB
  unsigned short* rank3 = (unsigned short*)(w + 284206464);  // 3.84 MB
  int* ssrc3 = (int*)(w + 288046464);               // 7.68 MB
  float* pblk3 = (float*)(w + 295726464);           // 2.4 MB
  float* pblk2_3 = (float*)(w + 298128768);         // 192 KB
  float* scsh3 = (float*)(w + 298325376);           // 3 KB

  __bf16* Wp1p = wpk;
  __bf16* Ws1p = wpk + 16384;
  __bf16* Wn1p = wpk + 2 * 16384;
  __bf16* Wp2p = wpk + 3 * 16384;
  __bf16* Ws2p = wpk + 4 * 16384;
  __bf16* Wn2p = wpk + 5 * 16384;

  const dim3 blk(256);
  const int edgeGrid = (NEDGES + 255) / 256;             // 2500
  const int aggGrid = (NNODES * 16 + 255) / 256;         // 6250
  const int degZeroGrid = (3 * NNODES / 4 + 255) / 256;  // 293

  // pack all weights in one dispatch
  packw6_k<<<48, blk, 0, stream>>>(Wp1, Ws1, Wn1, Wp2, Ws2, Wn2, wpk);

  // batched edge bucketing (counting sort by dst) for all 3 graphs
  zero_k<<<degZeroGrid, blk, 0, stream>>>((float4*)deg3, 3L * NNODES / 4);
  hist_rank3_k<<<dim3(edgeGrid, 3), blk, 0, stream>>>(edges, deg3, rank3);
  blocksum3_k<<<dim3(NB, 3), blk, 0, stream>>>(deg3, bsum3);
  scanb3_k<<<dim3(1, 3), dim3(512), 0, stream>>>(bsum3, boffs3, offs3);
  offsets3_k<<<dim3(NB, 3), blk, 0, stream>>>(deg3, boffs3, offs3);
  scat3_k<<<dim3(edgeGrid, 3), blk, 0, stream>>>(edges, offs3, rank3, ssrc3);

  // head: m1 = relu(feat@Wp1^T + bp1) (bf16), plus featb = bf16(feat)
  gemm_k<0, 0, false, true, true, false, true><<<dim3(GEMM_GRID, 1), blk, 0, stream>>>(
      feat, 0, nullptr, 0, Wp1p, nullptr, bp1, nullptr, m1, 0, nullptr, featb, NNODES);

  // layer 1 (all 3 graphs batched):
  // agg1[g] = segmax_g(m1);  h1[g] = agg1[g]@Wn1^T + featb@Ws1^T + b1 (+BN stats)
  agg_k<<<dim3(aggGrid, 3), blk, 0, stream>>>((const unsigned short*)m1, 0L,
                                              ssrc3, offs3, (unsigned short*)aggb3);
  gemm_k<1, 1, true, false, true, true, false><<<dim3(GEMM_GRID, 3), blk, 0, stream>>>(
      aggb3, SZ_BF, featb, 0, Wn1p, Ws1p, b1, nullptr, h1b3, SZ_BF, pblk3, nullptr, NNODES);
  bn_red1_k<<<dim3(64, 3), blk, 0, stream>>>(pblk3, pblk2_3);
  bn_final2_k<<<dim3(1, 3), blk, 0, stream>>>(pblk2_3, gamma, beta, scsh3);

  // layer 2 (batched): m2[g] = relu(bnrelu(h1[g])@Wp2^T + bp2)
  gemm_k<3, 0, false, true, true, false, false><<<dim3(GEMM_GRID, 3), blk, 0, stream>>>(
      h1b3, SZ_BF, nullptr, 0, Wp2p, nullptr, bp2, scsh3, m2_3, SZ_BF, nullptr, nullptr, NNODES);
  agg_k<<<dim3(aggGrid, 3), blk, 0, stream>>>((const unsigned short*)m2_3,
                                              (long)NNODES * FD, ssrc3, offs3,
                                              (unsigned short*)aggb3);
  // out[g] = bnrelu(h1[g])@Ws2^T + agg2[g]@Wn2^T + b2  -> d_out (f32)
  gemm_k<3, 1, true, false, false, false, false><<<dim3(GEMM_GRID, 3), blk, 0, stream>>>(
      h1b3, SZ_BF, aggb3, SZ_BF, Ws2p, Wn2p, b2, scsh3, d_out, SZ_F32, nullptr, nullptr, NNODES);
}